// Round 13
// baseline (359.139 us; speedup 1.0000x reference)
//
#include <hip/hip_runtime.h>

#define NODE 30000
#define NODE_P 30080   // padded to 235*128
#define HID 128
#define NE 600000
#define NB 4096
#define NROWS 8192
#define NSBLK 235      // nodestats blocks (128 nodes each)
#define NCHUNK 16      // k_fused node chunks
#define NRND 235       // k_fused rounds of 128 nodes over NODE_P

typedef short bf16x8 __attribute__((ext_vector_type(8)));
typedef float f32x4 __attribute__((ext_vector_type(4)));
typedef unsigned short u16x8 __attribute__((ext_vector_type(8)));

__device__ __forceinline__ unsigned short f2bf(float x) {
  union { float f; unsigned u; } v; v.f = x;
  unsigned r = v.u + 0x7fffu + ((v.u >> 16) & 1u);
  return (unsigned short)(r >> 16);
}
__device__ __forceinline__ float bf2f(unsigned short h) {
  union { unsigned u; float f; } v; v.u = ((unsigned)h) << 16; return v.f;
}
__device__ __forceinline__ float fast_exp2(float x) {
#if __has_builtin(__builtin_amdgcn_exp2f)
  return __builtin_amdgcn_exp2f(x);
#else
  return exp2f(x);
#endif
}

// ---------------- K1: cast emb->bf16 (blocks 0..3749) + degree count + edge position ----------------
__global__ void k_prep(const float* __restrict__ emb, unsigned short* __restrict__ embb,
                       const int* __restrict__ rows, int* __restrict__ deg,
                       int* __restrict__ epos) {
  int b = blockIdx.x;
  if (b < 3750) {
    int i = (b * 256 + threadIdx.x) * 4;   // covers 3.84M exactly
    float4 v = *(const float4*)(emb + i);
    ushort4 o;
    o.x = f2bf(v.x); o.y = f2bf(v.y); o.z = f2bf(v.z); o.w = f2bf(v.w);
    *(ushort4*)(embb + i) = o;
  } else {
    int e = (b - 3750) * 256 + threadIdx.x;
    if (e < NE) epos[e] = atomicAdd(&deg[rows[e]], 1);   // position doubles as scatter slot
  }
}

// ---------------- K2: exclusive scan, LDS-staged (coalesced in/out) ----------------
__global__ void __launch_bounds__(1024) k_scan(const int* __restrict__ deg,
                                               int* __restrict__ off) {
  __shared__ int ldeg[NODE];   // 120 KB
  __shared__ int part[1024];
  int t = threadIdx.x;
  for (int i = t; i < NODE; i += 1024) ldeg[i] = deg[i];
  __syncthreads();
  int base = t * 30;
  int s = 0;
  for (int i = 0; i < 30; i++) { int idx = base + i; if (idx < NODE) s += ldeg[idx]; }
  part[t] = s; __syncthreads();
  for (int d = 1; d < 1024; d <<= 1) {
    int v = (t >= d) ? part[t - d] : 0;
    __syncthreads();
    part[t] += v;
    __syncthreads();
  }
  int run = (t == 0) ? 0 : part[t - 1];
  for (int i = 0; i < 30; i++) {
    int idx = base + i;
    if (idx < NODE) { int d = ldeg[idx]; ldeg[idx] = run; run += d; }
  }
  __syncthreads();
  for (int i = t; i < NODE; i += 1024) off[i] = ldeg[i];
  if (t == 1023) off[NODE] = run;   // == NE
}

// ---------------- K3: scatter edges into CSR buckets (NO atomics — epos precomputed) ----------------
__global__ void k_scatter(const int* __restrict__ rows, const int* __restrict__ cols,
                          const int* __restrict__ off, const int* __restrict__ epos,
                          int* __restrict__ colidx) {
  int e = blockIdx.x * 256 + threadIdx.x;
  if (e < NE) {
    int r = rows[e];
    colidx[off[r] + epos[e]] = cols[e];
  }
}

// ---------------- K4: per-row aggregation (1 wave = 1 row; 8-deep main, predicated 4-deep tail) ----------------
__global__ void __launch_bounds__(256) k_aggregate(const unsigned short* __restrict__ embb,
    const int* __restrict__ off, const int* __restrict__ colidx,
    unsigned short* __restrict__ featb, float* __restrict__ sqn,
    float* __restrict__ tsqn) {
  int wv = threadIdx.x >> 6, lane = threadIdx.x & 63;
  int r = blockIdx.x * 4 + wv;
  if (r >= NODE) {             // pad rows NODE..NODE_P-1
    ushort2 z; z.x = 0; z.y = 0;
    *(ushort2*)(featb + (size_t)r * HID + lane * 2) = z;
    if (lane == 0) tsqn[r] = -1e30f;
    return;
  }
  int e0 = off[r], e1 = off[r + 1];
  float a0 = 0.f, a1 = 0.f, b0 = 0.f, b1 = 0.f;
  float c0a = 0.f, c1a = 0.f, d0 = 0.f, d1 = 0.f;
  int e = e0;
  for (; e + 7 < e1; e += 8) {
    int n0 = colidx[e],     n1 = colidx[e + 1], n2 = colidx[e + 2], n3 = colidx[e + 3];
    int n4 = colidx[e + 4], n5 = colidx[e + 5], n6 = colidx[e + 6], n7 = colidx[e + 7];
    ushort2 v0 = *(const ushort2*)(embb + (size_t)n0 * HID + lane * 2);
    ushort2 v1 = *(const ushort2*)(embb + (size_t)n1 * HID + lane * 2);
    ushort2 v2 = *(const ushort2*)(embb + (size_t)n2 * HID + lane * 2);
    ushort2 v3 = *(const ushort2*)(embb + (size_t)n3 * HID + lane * 2);
    ushort2 v4 = *(const ushort2*)(embb + (size_t)n4 * HID + lane * 2);
    ushort2 v5 = *(const ushort2*)(embb + (size_t)n5 * HID + lane * 2);
    ushort2 v6 = *(const ushort2*)(embb + (size_t)n6 * HID + lane * 2);
    ushort2 v7 = *(const ushort2*)(embb + (size_t)n7 * HID + lane * 2);
    a0 += bf2f(v0.x) + bf2f(v4.x); a1 += bf2f(v0.y) + bf2f(v4.y);
    b0 += bf2f(v1.x) + bf2f(v5.x); b1 += bf2f(v1.y) + bf2f(v5.y);
    c0a += bf2f(v2.x) + bf2f(v6.x); c1a += bf2f(v2.y) + bf2f(v6.y);
    d0 += bf2f(v3.x) + bf2f(v7.x); d1 += bf2f(v3.y) + bf2f(v7.y);
  }
  for (; e < e1; e += 4) {
    bool m1 = (e + 1 < e1), m2 = (e + 2 < e1), m3 = (e + 3 < e1);
    int n0 = colidx[e];
    int n1 = colidx[m1 ? e + 1 : e];
    int n2 = colidx[m2 ? e + 2 : e];
    int n3 = colidx[m3 ? e + 3 : e];
    ushort2 v0 = *(const ushort2*)(embb + (size_t)n0 * HID + lane * 2);
    ushort2 v1 = *(const ushort2*)(embb + (size_t)n1 * HID + lane * 2);
    ushort2 v2 = *(const ushort2*)(embb + (size_t)n2 * HID + lane * 2);
    ushort2 v3 = *(const ushort2*)(embb + (size_t)n3 * HID + lane * 2);
    a0 += bf2f(v0.x);                  a1 += bf2f(v0.y);
    b0 += m1 ? bf2f(v1.x) : 0.f;       b1 += m1 ? bf2f(v1.y) : 0.f;
    c0a += m2 ? bf2f(v2.x) : 0.f;      c1a += m2 ? bf2f(v2.y) : 0.f;
    d0 += m3 ? bf2f(v3.x) : 0.f;       d1 += m3 ? bf2f(v3.y) : 0.f;
  }
  a0 += b0 + c0a + d0; a1 += b1 + c1a + d1;
  int dg = e1 - e0;
  float w = 1.0f / (float)(dg > 0 ? dg : 1);
  a0 *= w; a1 *= w;
  ushort2 hb; hb.x = f2bf(a0); hb.y = f2bf(a1);
  *(ushort2*)(featb + (size_t)r * HID + lane * 2) = hb;
  float q0 = bf2f(hb.x), q1 = bf2f(hb.y);
  float ss = q0 * q0 + q1 * q1;
  for (int m = 1; m < 64; m <<= 1) ss += __shfl_xor(ss, m);
  if (lane == 0) { sqn[r] = ss; tsqn[r] = -0.5f * ss; }
}

// ---------------- K5: node stats: Gram partials (no atomics) + Fsum/Hsum/S1/S2 ----------------
__global__ void __launch_bounds__(256) k_nodestats(const unsigned short* __restrict__ featb,
    const float* __restrict__ sqn, float* __restrict__ Gpart,
    double* __restrict__ Fsum, double* __restrict__ Hsum, double* __restrict__ S12) {
  __shared__ unsigned short lds[128 * 136];
  __shared__ double red[256];
  int t = threadIdx.x;
  int n0 = blockIdx.x * 128;
  {
    int n = t >> 1, h = t & 1;
    unsigned short* dst = lds + n * 136 + h * 64;
    if (n0 + n < NODE) {
      const unsigned short* src = featb + (size_t)(n0 + n) * HID + h * 64;
      #pragma unroll
      for (int i = 0; i < 64; i += 8) *(u16x8*)(dst + i) = *(const u16x8*)(src + i);
    } else {
      u16x8 z = {0, 0, 0, 0, 0, 0, 0, 0};
      #pragma unroll
      for (int i = 0; i < 64; i += 8) *(u16x8*)(dst + i) = z;
    }
  }
  __syncthreads();
  int i0 = (t >> 4) * 8, j0 = (t & 15) * 8;
  float acc[8][8];
  #pragma unroll
  for (int i = 0; i < 8; i++)
    #pragma unroll
    for (int j = 0; j < 8; j++) acc[i][j] = 0.f;
  for (int r = 0; r < 128; r++) {
    const unsigned short* row = lds + r * 136;
    u16x8 va = *(const u16x8*)(row + i0);
    u16x8 vb = *(const u16x8*)(row + j0);
    float ai[8], aj[8];
    #pragma unroll
    for (int k = 0; k < 8; k++) { ai[k] = bf2f(va[k]); aj[k] = bf2f(vb[k]); }
    #pragma unroll
    for (int i = 0; i < 8; i++)
      #pragma unroll
      for (int j = 0; j < 8; j++) acc[i][j] = fmaf(ai[i], aj[j], acc[i][j]);
  }
  float* gp = Gpart + (size_t)blockIdx.x * 16384;
  #pragma unroll
  for (int i = 0; i < 8; i++) {
    f32x4 v0, v1;
    #pragma unroll
    for (int j = 0; j < 4; j++) { v0[j] = acc[i][j]; v1[j] = acc[i][4 + j]; }
    *(f32x4*)(gp + (i0 + i) * 128 + j0) = v0;
    *(f32x4*)(gp + (i0 + i) * 128 + j0 + 4) = v1;
  }
  int d = t & 127, hh = t >> 7;
  double fs = 0.0, hs = 0.0, s1 = 0.0, s2 = 0.0;
  for (int n = hh * 64; n < hh * 64 + 64; n++) {
    int gn = n0 + n;
    if (gn >= NODE) break;
    float v = bf2f(lds[n * 136 + d]);
    float q = sqn[gn];
    fs += (double)v;
    hs += (double)q * (double)v;
    if (d == 0) { s1 += (double)q; s2 += (double)q * (double)q; }
  }
  red[t] = fs; __syncthreads();
  if (hh == 0) atomicAdd(&Fsum[d], red[t] + red[t + 128]);
  __syncthreads();
  red[t] = hs; __syncthreads();
  if (hh == 0) atomicAdd(&Hsum[d], red[t] + red[t + 128]);
  if (t == 0) { atomicAdd(&S12[0], s1); atomicAdd(&S12[1], s2); }
  if (t == 128) { atomicAdd(&S12[0], s1); atomicAdd(&S12[1], s2); }
}

// ---------------- K5b: reduce Gram partials (64 blocks, coalesced) ----------------
__global__ void __launch_bounds__(256) k_greduce(const float* __restrict__ Gpart,
                                                 float* __restrict__ G) {
  int idx = blockIdx.x * 256 + threadIdx.x;   // 64 blocks cover 16384
  float s = 0.f;
  for (int b = 0; b < NSBLK; b++)
    s += Gpart[(size_t)b * 16384 + idx];
  G[idx] = s;
}

// ---------------- K6: per-pair coeffs (f64), 8 pairs/block (512 thr), G staged in LDS ----------------
__global__ void __launch_bounds__(512) k_pairstats(const int* __restrict__ tp,
    const unsigned short* __restrict__ featb, const float* __restrict__ sqn,
    const float* __restrict__ G, const double* __restrict__ Fsum,
    const double* __restrict__ Hsum, const double* __restrict__ S12,
    float* __restrict__ coefA, float* __restrict__ coefG, float* __restrict__ corr) {
  __shared__ float Gs[128 * 128];            // 64 KB — read G once per block
  __shared__ float shl[8][128], shr[8][128];
  int t = threadIdx.x;
  for (int i = t * 4; i < 16384; i += 2048)
    *(f32x4*)(Gs + i) = *(const f32x4*)(G + i);
  int wv = t >> 6, lane = t & 63;
  int b = blockIdx.x * 8 + wv;
  int l = tp[2 * b], r = tp[2 * b + 1];
  ushort2 lu = *(const ushort2*)(featb + (size_t)l * HID + lane * 2);
  ushort2 ru = *(const ushort2*)(featb + (size_t)r * HID + lane * 2);
  float2 lv, rv;
  lv.x = bf2f(lu.x); lv.y = bf2f(lu.y);
  rv.x = bf2f(ru.x); rv.y = bf2f(ru.y);
  shl[wv][lane * 2] = lv.x; shl[wv][lane * 2 + 1] = lv.y;
  shr[wv][lane * 2] = rv.x; shr[wv][lane * 2 + 1] = rv.y;
  __syncthreads();
  float dx = lv.x - rv.x, dy = lv.y - rv.y;
  float ps = dx * dx + dy * dy;
  for (int m = 1; m < 64; m <<= 1) ps += __shfl_xor(ps, m);
  double ql0 = 0, ql1 = 0, qr0 = 0, qr1 = 0;
  for (int j = 0; j < 128; j++) {
    float2 g = *(const float2*)(Gs + j * 128 + lane * 2);
    double slj = (double)shl[wv][j], srj = (double)shr[wv][j];
    ql0 += (double)g.x * slj; ql1 += (double)g.y * slj;
    qr0 += (double)g.x * srj; qr1 += (double)g.y * srj;
  }
  double lx0 = lv.x, lx1 = lv.y, rx0 = rv.x, rx1 = rv.y;
  double lG = lx0 * ql0 + lx1 * ql1;
  double rG = rx0 * qr0 + rx1 * qr1;
  double f0 = Fsum[lane * 2], f1 = Fsum[lane * 2 + 1];
  double h0 = Hsum[lane * 2], h1 = Hsum[lane * 2 + 1];
  double lF = lx0 * f0 + lx1 * f1, rF = rx0 * f0 + rx1 * f1;
  double lH = lx0 * h0 + lx1 * h1, rH = rx0 * h0 + rx1 * h1;
  for (int m = 1; m < 64; m <<= 1) {
    lG += __shfl_xor(lG, m); rG += __shfl_xor(rG, m);
    lF += __shfl_xor(lF, m); rF += __shfl_xor(rF, m);
    lH += __shfl_xor(lH, m); rH += __shfl_xor(rH, m);
  }
  if (lane == 0) {
    const double GAM = 3.0, LAM = 30.0, L2E = 1.4426950408889634;
    double pos = (double)ps;
    double S1 = S12[0], S2 = S12[1];
    double sl = (double)sqn[l], sr = (double)sqn[r];
    double N = (double)NODE;
    for (int side = 0; side < 2; side++) {
      double u  = pos + GAM - (side ? sr : sl);
      double F  = side ? rF : lF;
      double Gq = side ? rG : lG;
      double H  = side ? rH : lH;
      double Sx  = N * u - S1 + 2.0 * F;
      double Sxx = N * u * u + S2 + 4.0 * Gq - 2.0 * u * S1 + 4.0 * u * F - 4.0 * H;
      double xl = pos + GAM;
      double xr2 = GAM;
      double Sxm, Sxxm;
      if (l != r) { Sxm = Sx - xl - xr2; Sxxm = Sxx - xl * xl - xr2 * xr2; }
      else        { Sxm = Sx - 2.0 * GAM; Sxxm = Sxx; }
      double mn = Sxm / N;
      double var = Sxxm / N - mn * mn;
      double sd = sqrt(var);
      double alpha = 2.0 * LAM / sd;
      double g2 = LAM * (u - mn) / sd;
      double cr;
      if (l != r)
        cr = exp(LAM * (xl - mn) / sd) + exp(LAM * (GAM - mn) / sd)
             - 2.0 * exp(LAM * (0.0 - mn) / sd);
      else
        cr = exp(LAM * (GAM - mn) / sd) - exp(LAM * (-GAM - mn) / sd);
      int row = b + side * NB;
      coefA[row] = (float)(alpha * L2E);
      coefG[row] = (float)(g2 * L2E);
      corr[row]  = (float)cr;
    }
  }
}

// ---------------- K7: fused bf16-MFMA GEMM + exp-sum + last-block final reduction ----------------
__global__ void __launch_bounds__(256, 2) k_fused(const int* __restrict__ tp,
    const unsigned short* __restrict__ featb, const float* __restrict__ tsqn,
    const float* __restrict__ coefA, const float* __restrict__ coefG,
    float* __restrict__ lsum, const float* __restrict__ corr,
    int* __restrict__ done, float* __restrict__ out) {
  __shared__ unsigned short bt[2][128 * 128];   // [buf][row*128 + phys_chunk*8]
  __shared__ float ts[2][128];
  int t = threadIdx.x;
  int wv = t >> 6, lane = t & 63;
  int chunk = blockIdx.x >> 5;    // 0..15 (consecutive blocks share chunk)
  int rg = blockIdx.x & 31;       // 0..31
  int mw = rg * 4 + wv;           // 0..127, 64 rows each
  int quad = lane >> 4, c16 = lane & 15;

  bf16x8 af[4][4];
  float cA[4][4], cG[4][4];
  #pragma unroll
  for (int f = 0; f < 4; f++) {
    int row = mw * 64 + f * 16 + c16;
    int node = (row < NB) ? tp[2 * row] : tp[2 * (row - NB) + 1];
    const unsigned short* src = featb + (size_t)node * HID + quad * 8;
    #pragma unroll
    for (int kc = 0; kc < 4; kc++)
      af[f][kc] = *(const bf16x8*)(src + kc * 32);
    int cr0 = mw * 64 + f * 16 + quad * 4;
    #pragma unroll
    for (int i = 0; i < 4; i++) { cA[f][i] = coefA[cr0 + i]; cG[f][i] = coefG[cr0 + i]; }
  }
  float acc[4][4];
  #pragma unroll
  for (int f = 0; f < 4; f++)
    #pragma unroll
    for (int i = 0; i < 4; i++) acc[f][i] = 0.f;

  int r0 = (NRND * chunk) / NCHUNK, r1 = (NRND * (chunk + 1)) / NCHUNK;

  u16x8 g[8];
  float gtv = 0.f;
  {
    int n0 = r0 * 128;
    #pragma unroll
    for (int i = 0; i < 8; i++) {
      int gi = i * 256 + t, lr = gi >> 4, c = gi & 15;
      g[i] = *(const u16x8*)(featb + (size_t)(n0 + lr) * HID + c * 8);
    }
    if (t < 128) gtv = tsqn[n0 + t];
  }
  #pragma unroll
  for (int i = 0; i < 8; i++) {
    int gi = i * 256 + t, lr = gi >> 4, c = gi & 15;
    *(u16x8*)(&bt[0][lr * 128 + ((c ^ (lr & 15)) * 8)]) = g[i];
  }
  if (t < 128) ts[0][t] = gtv;
  __syncthreads();

  int buf = 0;
  for (int r = r0; r < r1; r++) {
    if (r + 1 < r1) {
      int n0 = (r + 1) * 128;
      #pragma unroll
      for (int i = 0; i < 8; i++) {
        int gi = i * 256 + t, lr = gi >> 4, c = gi & 15;
        g[i] = *(const u16x8*)(featb + (size_t)(n0 + lr) * HID + c * 8);
      }
      if (t < 128) gtv = tsqn[n0 + t];
    }
    #pragma unroll 2
    for (int s = 0; s < 8; s++) {
      int lr = s * 16 + c16;
      const unsigned short* base = &bt[buf][lr * 128];
      bf16x8 b0 = *(const bf16x8*)(base + (((0 * 4 + quad) ^ c16) * 8));
      bf16x8 b1 = *(const bf16x8*)(base + (((1 * 4 + quad) ^ c16) * 8));
      bf16x8 b2 = *(const bf16x8*)(base + (((2 * 4 + quad) ^ c16) * 8));
      bf16x8 b3 = *(const bf16x8*)(base + (((3 * 4 + quad) ^ c16) * 8));
      float tsq = ts[buf][s * 16 + c16];
      #pragma unroll
      for (int f = 0; f < 4; f++) {
        f32x4 c = {tsq, tsq, tsq, tsq};   // seed: D = S + tsq from the MFMA
        c = __builtin_amdgcn_mfma_f32_16x16x32_bf16(af[f][0], b0, c, 0, 0, 0);
        c = __builtin_amdgcn_mfma_f32_16x16x32_bf16(af[f][1], b1, c, 0, 0, 0);
        c = __builtin_amdgcn_mfma_f32_16x16x32_bf16(af[f][2], b2, c, 0, 0, 0);
        c = __builtin_amdgcn_mfma_f32_16x16x32_bf16(af[f][3], b3, c, 0, 0, 0);
        #pragma unroll
        for (int i = 0; i < 4; i++)
          acc[f][i] += fast_exp2(fmaf(cA[f][i], c[i], cG[f][i]));
      }
    }
    if (r + 1 < r1) {
      #pragma unroll
      for (int i = 0; i < 8; i++) {
        int gi = i * 256 + t, lr = gi >> 4, c = gi & 15;
        *(u16x8*)(&bt[buf ^ 1][lr * 128 + ((c ^ (lr & 15)) * 8)]) = g[i];
      }
      if (t < 128) ts[buf ^ 1][t] = gtv;
    }
    __syncthreads();
    buf ^= 1;
  }

  #pragma unroll
  for (int f = 0; f < 4; f++)
    #pragma unroll
    for (int i = 0; i < 4; i++) {
      float v = acc[f][i];
      v += __shfl_xor(v, 1); v += __shfl_xor(v, 2);
      v += __shfl_xor(v, 4); v += __shfl_xor(v, 8);
      acc[f][i] = v;
    }
  int f = c16 >> 2, i = c16 & 3;
  int row = mw * 64 + f * 16 + quad * 4 + i;
  atomicAdd(&lsum[row], acc[f][i]);

  // ---- last-block final reduction (replaces k_final launch) ----
  __threadfence();
  __shared__ int isLast;
  if (t == 0) isLast = (atomicAdd(done, 1) == (int)gridDim.x - 1);
  __syncthreads();
  if (isLast) {
    __shared__ double red[256];
    double s = 0.0;
    for (int rr = t; rr < NROWS; rr += 256) {
      float lv = atomicAdd(&lsum[rr], 0.0f);     // coherent device-scope read
      s += 10.0 + log((double)lv - (double)corr[rr]);
    }
    red[t] = s; __syncthreads();
    for (int d = 128; d > 0; d >>= 1) { if (t < d) red[t] += red[t + d]; __syncthreads(); }
    if (t == 0) out[0] = (float)(red[0] / (double)NB);
  }
}

extern "C" void kernel_launch(void* const* d_in, const int* in_sizes, int n_in,
                              void* d_out, int out_size, void* d_ws, size_t ws_size,
                              hipStream_t stream) {
  (void)in_sizes; (void)n_in; (void)out_size; (void)ws_size;
  const int* tp    = (const int*)d_in[0];
  const int* adj   = (const int*)d_in[1];
  const float* emb = (const float*)d_in[2];
  const int* rows = adj;
  const int* cols = adj + NE;

  char* ws = (char*)d_ws;
  size_t o = 0;
  auto alloc = [&](size_t bytes) -> char* {
    char* p = ws + o;
    o = (o + bytes + 255) & ~(size_t)255;
    return p;
  };
  // zero-initialized region (single memset)
  int* deg       = (int*)alloc(NODE * 4);
  double* Fsum   = (double*)alloc(128 * 8);
  double* Hsum   = (double*)alloc(128 * 8);
  double* S12    = (double*)alloc(2 * 8);
  float* lsum    = (float*)alloc(NROWS * 4);
  int* done      = (int*)alloc(4);
  size_t zero_bytes = o;
  // rest
  float* G       = (float*)alloc(128 * 128 * 4);
  float* Gpart   = (float*)alloc((size_t)NSBLK * 16384 * 4);
  int* off       = (int*)alloc((NODE + 1) * 4);
  float* sqn     = (float*)alloc(NODE * 4);
  float* tsqn    = (float*)alloc((size_t)NODE_P * 4);
  float* coefA   = (float*)alloc(NROWS * 4);
  float* coefG   = (float*)alloc(NROWS * 4);
  float* corr    = (float*)alloc(NROWS * 4);
  int* colidx    = (int*)alloc((size_t)NE * 4);
  int* epos      = (int*)alloc((size_t)NE * 4);
  unsigned short* featb = (unsigned short*)alloc((size_t)NODE_P * HID * 2);
  unsigned short* embb  = (unsigned short*)alloc((size_t)NODE * HID * 2);

  hipMemsetAsync(d_ws, 0, zero_bytes, stream);
  k_prep<<<3750 + (NE + 255) / 256, 256, 0, stream>>>(emb, embb, rows, deg, epos);
  k_scan<<<1, 1024, 0, stream>>>(deg, off);
  k_scatter<<<(NE + 255) / 256, 256, 0, stream>>>(rows, cols, off, epos, colidx);
  k_aggregate<<<NODE_P / 4, 256, 0, stream>>>(embb, off, colidx, featb, sqn, tsqn);
  k_nodestats<<<NSBLK, 256, 0, stream>>>(featb, sqn, Gpart, Fsum, Hsum, S12);
  k_greduce<<<64, 256, 0, stream>>>(Gpart, G);
  k_pairstats<<<NB / 8, 512, 0, stream>>>(tp, featb, sqn, G, Fsum, Hsum, S12, coefA, coefG, corr);
  k_fused<<<NCHUNK * 32, 256, 0, stream>>>(tp, featb, tsqn, coefA, coefG,
                                           lsum, corr, done, (float*)d_out);
}

// Round 14
// 308.222 us; speedup vs baseline: 1.1652x; 1.1652x over previous
//
#include <hip/hip_runtime.h>

#define NODE 30000
#define NODE_P 30080   // padded to 235*128
#define HID 128
#define NE 600000
#define NB 4096
#define NROWS 8192
#define NSBLK 235      // nodestats blocks (128 nodes each)
#define NCHUNK 16      // k_fused node chunks
#define NRND 235       // k_fused rounds of 128 nodes over NODE_P

typedef short bf16x8 __attribute__((ext_vector_type(8)));
typedef float f32x4 __attribute__((ext_vector_type(4)));
typedef unsigned short u16x8 __attribute__((ext_vector_type(8)));

__device__ __forceinline__ unsigned short f2bf(float x) {
  union { float f; unsigned u; } v; v.f = x;
  unsigned r = v.u + 0x7fffu + ((v.u >> 16) & 1u);
  return (unsigned short)(r >> 16);
}
__device__ __forceinline__ float bf2f(unsigned short h) {
  union { unsigned u; float f; } v; v.u = ((unsigned)h) << 16; return v.f;
}
__device__ __forceinline__ float fast_exp2(float x) {
#if __has_builtin(__builtin_amdgcn_exp2f)
  return __builtin_amdgcn_exp2f(x);
#else
  return exp2f(x);
#endif
}

// ---------------- K1: cast emb->bf16 (blocks 0..3749) + degree count + edge position ----------------
__global__ void k_prep(const float* __restrict__ emb, unsigned short* __restrict__ embb,
                       const int* __restrict__ rows, int* __restrict__ deg,
                       int* __restrict__ epos) {
  int b = blockIdx.x;
  if (b < 3750) {
    int i = (b * 256 + threadIdx.x) * 4;   // covers 3.84M exactly
    float4 v = *(const float4*)(emb + i);
    ushort4 o;
    o.x = f2bf(v.x); o.y = f2bf(v.y); o.z = f2bf(v.z); o.w = f2bf(v.w);
    *(ushort4*)(embb + i) = o;
  } else {
    int e = (b - 3750) * 256 + threadIdx.x;
    if (e < NE) epos[e] = atomicAdd(&deg[rows[e]], 1);   // position doubles as scatter slot
  }
}

// ---------------- K2: exclusive scan, LDS-staged (coalesced in/out) ----------------
__global__ void __launch_bounds__(1024) k_scan(const int* __restrict__ deg,
                                               int* __restrict__ off) {
  __shared__ int ldeg[NODE];   // 120 KB
  __shared__ int part[1024];
  int t = threadIdx.x;
  for (int i = t; i < NODE; i += 1024) ldeg[i] = deg[i];
  __syncthreads();
  int base = t * 30;
  int s = 0;
  for (int i = 0; i < 30; i++) { int idx = base + i; if (idx < NODE) s += ldeg[idx]; }
  part[t] = s; __syncthreads();
  for (int d = 1; d < 1024; d <<= 1) {
    int v = (t >= d) ? part[t - d] : 0;
    __syncthreads();
    part[t] += v;
    __syncthreads();
  }
  int run = (t == 0) ? 0 : part[t - 1];
  for (int i = 0; i < 30; i++) {
    int idx = base + i;
    if (idx < NODE) { int d = ldeg[idx]; ldeg[idx] = run; run += d; }
  }
  __syncthreads();
  for (int i = t; i < NODE; i += 1024) off[i] = ldeg[i];
  if (t == 1023) off[NODE] = run;   // == NE
}

// ---------------- K3: scatter edges into CSR buckets (NO atomics — epos precomputed) ----------------
__global__ void k_scatter(const int* __restrict__ rows, const int* __restrict__ cols,
                          const int* __restrict__ off, const int* __restrict__ epos,
                          int* __restrict__ colidx) {
  int e = blockIdx.x * 256 + threadIdx.x;
  if (e < NE) {
    int r = rows[e];
    colidx[off[r] + epos[e]] = cols[e];
  }
}

// ---------------- K4: per-row aggregation (1 wave = 1 row; 8-deep main, predicated 4-deep tail) ----------------
__global__ void __launch_bounds__(256) k_aggregate(const unsigned short* __restrict__ embb,
    const int* __restrict__ off, const int* __restrict__ colidx,
    unsigned short* __restrict__ featb, float* __restrict__ sqn,
    float* __restrict__ tsqn) {
  int wv = threadIdx.x >> 6, lane = threadIdx.x & 63;
  int r = blockIdx.x * 4 + wv;
  if (r >= NODE) {             // pad rows NODE..NODE_P-1
    ushort2 z; z.x = 0; z.y = 0;
    *(ushort2*)(featb + (size_t)r * HID + lane * 2) = z;
    if (lane == 0) tsqn[r] = -1e30f;
    return;
  }
  int e0 = off[r], e1 = off[r + 1];
  float a0 = 0.f, a1 = 0.f, b0 = 0.f, b1 = 0.f;
  float c0a = 0.f, c1a = 0.f, d0 = 0.f, d1 = 0.f;
  int e = e0;
  for (; e + 7 < e1; e += 8) {
    int n0 = colidx[e],     n1 = colidx[e + 1], n2 = colidx[e + 2], n3 = colidx[e + 3];
    int n4 = colidx[e + 4], n5 = colidx[e + 5], n6 = colidx[e + 6], n7 = colidx[e + 7];
    ushort2 v0 = *(const ushort2*)(embb + (size_t)n0 * HID + lane * 2);
    ushort2 v1 = *(const ushort2*)(embb + (size_t)n1 * HID + lane * 2);
    ushort2 v2 = *(const ushort2*)(embb + (size_t)n2 * HID + lane * 2);
    ushort2 v3 = *(const ushort2*)(embb + (size_t)n3 * HID + lane * 2);
    ushort2 v4 = *(const ushort2*)(embb + (size_t)n4 * HID + lane * 2);
    ushort2 v5 = *(const ushort2*)(embb + (size_t)n5 * HID + lane * 2);
    ushort2 v6 = *(const ushort2*)(embb + (size_t)n6 * HID + lane * 2);
    ushort2 v7 = *(const ushort2*)(embb + (size_t)n7 * HID + lane * 2);
    a0 += bf2f(v0.x) + bf2f(v4.x); a1 += bf2f(v0.y) + bf2f(v4.y);
    b0 += bf2f(v1.x) + bf2f(v5.x); b1 += bf2f(v1.y) + bf2f(v5.y);
    c0a += bf2f(v2.x) + bf2f(v6.x); c1a += bf2f(v2.y) + bf2f(v6.y);
    d0 += bf2f(v3.x) + bf2f(v7.x); d1 += bf2f(v3.y) + bf2f(v7.y);
  }
  for (; e < e1; e += 4) {
    bool m1 = (e + 1 < e1), m2 = (e + 2 < e1), m3 = (e + 3 < e1);
    int n0 = colidx[e];
    int n1 = colidx[m1 ? e + 1 : e];
    int n2 = colidx[m2 ? e + 2 : e];
    int n3 = colidx[m3 ? e + 3 : e];
    ushort2 v0 = *(const ushort2*)(embb + (size_t)n0 * HID + lane * 2);
    ushort2 v1 = *(const ushort2*)(embb + (size_t)n1 * HID + lane * 2);
    ushort2 v2 = *(const ushort2*)(embb + (size_t)n2 * HID + lane * 2);
    ushort2 v3 = *(const ushort2*)(embb + (size_t)n3 * HID + lane * 2);
    a0 += bf2f(v0.x);                  a1 += bf2f(v0.y);
    b0 += m1 ? bf2f(v1.x) : 0.f;       b1 += m1 ? bf2f(v1.y) : 0.f;
    c0a += m2 ? bf2f(v2.x) : 0.f;      c1a += m2 ? bf2f(v2.y) : 0.f;
    d0 += m3 ? bf2f(v3.x) : 0.f;       d1 += m3 ? bf2f(v3.y) : 0.f;
  }
  a0 += b0 + c0a + d0; a1 += b1 + c1a + d1;
  int dg = e1 - e0;
  float w = 1.0f / (float)(dg > 0 ? dg : 1);
  a0 *= w; a1 *= w;
  ushort2 hb; hb.x = f2bf(a0); hb.y = f2bf(a1);
  *(ushort2*)(featb + (size_t)r * HID + lane * 2) = hb;
  float q0 = bf2f(hb.x), q1 = bf2f(hb.y);
  float ss = q0 * q0 + q1 * q1;
  for (int m = 1; m < 64; m <<= 1) ss += __shfl_xor(ss, m);
  if (lane == 0) { sqn[r] = ss; tsqn[r] = -0.5f * ss; }
}

// ---------------- K5: node stats: Gram partials (no atomics) + Fsum/Hsum/S1/S2 ----------------
__global__ void __launch_bounds__(256) k_nodestats(const unsigned short* __restrict__ featb,
    const float* __restrict__ sqn, float* __restrict__ Gpart,
    double* __restrict__ Fsum, double* __restrict__ Hsum, double* __restrict__ S12) {
  __shared__ unsigned short lds[128 * 136];
  __shared__ double red[256];
  int t = threadIdx.x;
  int n0 = blockIdx.x * 128;
  {
    int n = t >> 1, h = t & 1;
    unsigned short* dst = lds + n * 136 + h * 64;
    if (n0 + n < NODE) {
      const unsigned short* src = featb + (size_t)(n0 + n) * HID + h * 64;
      #pragma unroll
      for (int i = 0; i < 64; i += 8) *(u16x8*)(dst + i) = *(const u16x8*)(src + i);
    } else {
      u16x8 z = {0, 0, 0, 0, 0, 0, 0, 0};
      #pragma unroll
      for (int i = 0; i < 64; i += 8) *(u16x8*)(dst + i) = z;
    }
  }
  __syncthreads();
  int i0 = (t >> 4) * 8, j0 = (t & 15) * 8;
  float acc[8][8];
  #pragma unroll
  for (int i = 0; i < 8; i++)
    #pragma unroll
    for (int j = 0; j < 8; j++) acc[i][j] = 0.f;
  for (int r = 0; r < 128; r++) {
    const unsigned short* row = lds + r * 136;
    u16x8 va = *(const u16x8*)(row + i0);
    u16x8 vb = *(const u16x8*)(row + j0);
    float ai[8], aj[8];
    #pragma unroll
    for (int k = 0; k < 8; k++) { ai[k] = bf2f(va[k]); aj[k] = bf2f(vb[k]); }
    #pragma unroll
    for (int i = 0; i < 8; i++)
      #pragma unroll
      for (int j = 0; j < 8; j++) acc[i][j] = fmaf(ai[i], aj[j], acc[i][j]);
  }
  float* gp = Gpart + (size_t)blockIdx.x * 16384;
  #pragma unroll
  for (int i = 0; i < 8; i++) {
    f32x4 v0, v1;
    #pragma unroll
    for (int j = 0; j < 4; j++) { v0[j] = acc[i][j]; v1[j] = acc[i][4 + j]; }
    *(f32x4*)(gp + (i0 + i) * 128 + j0) = v0;
    *(f32x4*)(gp + (i0 + i) * 128 + j0 + 4) = v1;
  }
  int d = t & 127, hh = t >> 7;
  double fs = 0.0, hs = 0.0, s1 = 0.0, s2 = 0.0;
  for (int n = hh * 64; n < hh * 64 + 64; n++) {
    int gn = n0 + n;
    if (gn >= NODE) break;
    float v = bf2f(lds[n * 136 + d]);
    float q = sqn[gn];
    fs += (double)v;
    hs += (double)q * (double)v;
    if (d == 0) { s1 += (double)q; s2 += (double)q * (double)q; }
  }
  red[t] = fs; __syncthreads();
  if (hh == 0) atomicAdd(&Fsum[d], red[t] + red[t + 128]);
  __syncthreads();
  red[t] = hs; __syncthreads();
  if (hh == 0) atomicAdd(&Hsum[d], red[t] + red[t + 128]);
  if (t == 0) { atomicAdd(&S12[0], s1); atomicAdd(&S12[1], s2); }
  if (t == 128) { atomicAdd(&S12[0], s1); atomicAdd(&S12[1], s2); }
}

// ---------------- K5b: reduce Gram partials (64 blocks, coalesced) ----------------
__global__ void __launch_bounds__(256) k_greduce(const float* __restrict__ Gpart,
                                                 float* __restrict__ G) {
  int idx = blockIdx.x * 256 + threadIdx.x;   // 64 blocks cover 16384
  float s = 0.f;
  for (int b = 0; b < NSBLK; b++)
    s += Gpart[(size_t)b * 16384 + idx];
  G[idx] = s;
}

// ---------------- K6: per-pair coeffs (f64), 8 pairs/block (512 thr), G staged in LDS ----------------
__global__ void __launch_bounds__(512) k_pairstats(const int* __restrict__ tp,
    const unsigned short* __restrict__ featb, const float* __restrict__ sqn,
    const float* __restrict__ G, const double* __restrict__ Fsum,
    const double* __restrict__ Hsum, const double* __restrict__ S12,
    float* __restrict__ coefA, float* __restrict__ coefG, float* __restrict__ corr) {
  __shared__ float Gs[128 * 128];            // 64 KB — read G once per block
  __shared__ float shl[8][128], shr[8][128];
  int t = threadIdx.x;
  for (int i = t * 4; i < 16384; i += 2048)
    *(f32x4*)(Gs + i) = *(const f32x4*)(G + i);
  int wv = t >> 6, lane = t & 63;
  int b = blockIdx.x * 8 + wv;
  int l = tp[2 * b], r = tp[2 * b + 1];
  ushort2 lu = *(const ushort2*)(featb + (size_t)l * HID + lane * 2);
  ushort2 ru = *(const ushort2*)(featb + (size_t)r * HID + lane * 2);
  float2 lv, rv;
  lv.x = bf2f(lu.x); lv.y = bf2f(lu.y);
  rv.x = bf2f(ru.x); rv.y = bf2f(ru.y);
  shl[wv][lane * 2] = lv.x; shl[wv][lane * 2 + 1] = lv.y;
  shr[wv][lane * 2] = rv.x; shr[wv][lane * 2 + 1] = rv.y;
  __syncthreads();
  float dx = lv.x - rv.x, dy = lv.y - rv.y;
  float ps = dx * dx + dy * dy;
  for (int m = 1; m < 64; m <<= 1) ps += __shfl_xor(ps, m);
  double ql0 = 0, ql1 = 0, qr0 = 0, qr1 = 0;
  for (int j = 0; j < 128; j++) {
    float2 g = *(const float2*)(Gs + j * 128 + lane * 2);
    double slj = (double)shl[wv][j], srj = (double)shr[wv][j];
    ql0 += (double)g.x * slj; ql1 += (double)g.y * slj;
    qr0 += (double)g.x * srj; qr1 += (double)g.y * srj;
  }
  double lx0 = lv.x, lx1 = lv.y, rx0 = rv.x, rx1 = rv.y;
  double lG = lx0 * ql0 + lx1 * ql1;
  double rG = rx0 * qr0 + rx1 * qr1;
  double f0 = Fsum[lane * 2], f1 = Fsum[lane * 2 + 1];
  double h0 = Hsum[lane * 2], h1 = Hsum[lane * 2 + 1];
  double lF = lx0 * f0 + lx1 * f1, rF = rx0 * f0 + rx1 * f1;
  double lH = lx0 * h0 + lx1 * h1, rH = rx0 * h0 + rx1 * h1;
  for (int m = 1; m < 64; m <<= 1) {
    lG += __shfl_xor(lG, m); rG += __shfl_xor(rG, m);
    lF += __shfl_xor(lF, m); rF += __shfl_xor(rF, m);
    lH += __shfl_xor(lH, m); rH += __shfl_xor(rH, m);
  }
  if (lane == 0) {
    const double GAM = 3.0, LAM = 30.0, L2E = 1.4426950408889634;
    double pos = (double)ps;
    double S1 = S12[0], S2 = S12[1];
    double sl = (double)sqn[l], sr = (double)sqn[r];
    double N = (double)NODE;
    for (int side = 0; side < 2; side++) {
      double u  = pos + GAM - (side ? sr : sl);
      double F  = side ? rF : lF;
      double Gq = side ? rG : lG;
      double H  = side ? rH : lH;
      double Sx  = N * u - S1 + 2.0 * F;
      double Sxx = N * u * u + S2 + 4.0 * Gq - 2.0 * u * S1 + 4.0 * u * F - 4.0 * H;
      double xl = pos + GAM;
      double xr2 = GAM;
      double Sxm, Sxxm;
      if (l != r) { Sxm = Sx - xl - xr2; Sxxm = Sxx - xl * xl - xr2 * xr2; }
      else        { Sxm = Sx - 2.0 * GAM; Sxxm = Sxx; }
      double mn = Sxm / N;
      double var = Sxxm / N - mn * mn;
      double sd = sqrt(var);
      double alpha = 2.0 * LAM / sd;
      double g2 = LAM * (u - mn) / sd;
      double cr;
      if (l != r)
        cr = exp(LAM * (xl - mn) / sd) + exp(LAM * (GAM - mn) / sd)
             - 2.0 * exp(LAM * (0.0 - mn) / sd);
      else
        cr = exp(LAM * (GAM - mn) / sd) - exp(LAM * (-GAM - mn) / sd);
      int row = b + side * NB;
      coefA[row] = (float)(alpha * L2E);
      coefG[row] = (float)(g2 * L2E);
      corr[row]  = (float)cr;
    }
  }
}

// ---------------- K7: fused bf16-MFMA GEMM + exp-sum (measured-best R11 config, no tail fusion) ----------------
__global__ void __launch_bounds__(256, 2) k_fused(const int* __restrict__ tp,
    const unsigned short* __restrict__ featb, const float* __restrict__ tsqn,
    const float* __restrict__ coefA, const float* __restrict__ coefG,
    float* __restrict__ lsum) {
  __shared__ unsigned short bt[2][128 * 128];   // [buf][row*128 + phys_chunk*8]
  __shared__ float ts[2][128];
  int t = threadIdx.x;
  int wv = t >> 6, lane = t & 63;
  int chunk = blockIdx.x >> 5;    // 0..15 (consecutive blocks share chunk)
  int rg = blockIdx.x & 31;       // 0..31
  int mw = rg * 4 + wv;           // 0..127, 64 rows each
  int quad = lane >> 4, c16 = lane & 15;

  bf16x8 af[4][4];
  float cA[4][4], cG[4][4];
  #pragma unroll
  for (int f = 0; f < 4; f++) {
    int row = mw * 64 + f * 16 + c16;
    int node = (row < NB) ? tp[2 * row] : tp[2 * (row - NB) + 1];
    const unsigned short* src = featb + (size_t)node * HID + quad * 8;
    #pragma unroll
    for (int kc = 0; kc < 4; kc++)
      af[f][kc] = *(const bf16x8*)(src + kc * 32);
    int cr0 = mw * 64 + f * 16 + quad * 4;
    #pragma unroll
    for (int i = 0; i < 4; i++) { cA[f][i] = coefA[cr0 + i]; cG[f][i] = coefG[cr0 + i]; }
  }
  float acc[4][4];
  #pragma unroll
  for (int f = 0; f < 4; f++)
    #pragma unroll
    for (int i = 0; i < 4; i++) acc[f][i] = 0.f;

  int r0 = (NRND * chunk) / NCHUNK, r1 = (NRND * (chunk + 1)) / NCHUNK;

  u16x8 g[8];
  float gtv = 0.f;
  {
    int n0 = r0 * 128;
    #pragma unroll
    for (int i = 0; i < 8; i++) {
      int gi = i * 256 + t, lr = gi >> 4, c = gi & 15;
      g[i] = *(const u16x8*)(featb + (size_t)(n0 + lr) * HID + c * 8);
    }
    if (t < 128) gtv = tsqn[n0 + t];
  }
  #pragma unroll
  for (int i = 0; i < 8; i++) {
    int gi = i * 256 + t, lr = gi >> 4, c = gi & 15;
    *(u16x8*)(&bt[0][lr * 128 + ((c ^ (lr & 15)) * 8)]) = g[i];
  }
  if (t < 128) ts[0][t] = gtv;
  __syncthreads();

  int buf = 0;
  for (int r = r0; r < r1; r++) {
    if (r + 1 < r1) {               // issue next round's global loads
      int n0 = (r + 1) * 128;
      #pragma unroll
      for (int i = 0; i < 8; i++) {
        int gi = i * 256 + t, lr = gi >> 4, c = gi & 15;
        g[i] = *(const u16x8*)(featb + (size_t)(n0 + lr) * HID + c * 8);
      }
      if (t < 128) gtv = tsqn[n0 + t];
    }
    #pragma unroll 2
    for (int s = 0; s < 8; s++) {
      int lr = s * 16 + c16;
      const unsigned short* base = &bt[buf][lr * 128];
      bf16x8 b0 = *(const bf16x8*)(base + (((0 * 4 + quad) ^ c16) * 8));
      bf16x8 b1 = *(const bf16x8*)(base + (((1 * 4 + quad) ^ c16) * 8));
      bf16x8 b2 = *(const bf16x8*)(base + (((2 * 4 + quad) ^ c16) * 8));
      bf16x8 b3 = *(const bf16x8*)(base + (((3 * 4 + quad) ^ c16) * 8));
      float tsq = ts[buf][s * 16 + c16];
      #pragma unroll
      for (int f = 0; f < 4; f++) {
        f32x4 c = {tsq, tsq, tsq, tsq};   // seed: D = S + tsq from the MFMA
        c = __builtin_amdgcn_mfma_f32_16x16x32_bf16(af[f][0], b0, c, 0, 0, 0);
        c = __builtin_amdgcn_mfma_f32_16x16x32_bf16(af[f][1], b1, c, 0, 0, 0);
        c = __builtin_amdgcn_mfma_f32_16x16x32_bf16(af[f][2], b2, c, 0, 0, 0);
        c = __builtin_amdgcn_mfma_f32_16x16x32_bf16(af[f][3], b3, c, 0, 0, 0);
        #pragma unroll
        for (int i = 0; i < 4; i++)
          acc[f][i] += fast_exp2(fmaf(cA[f][i], c[i], cG[f][i]));
      }
    }
    if (r + 1 < r1) {               // write next round into other buffer
      #pragma unroll
      for (int i = 0; i < 8; i++) {
        int gi = i * 256 + t, lr = gi >> 4, c = gi & 15;
        *(u16x8*)(&bt[buf ^ 1][lr * 128 + ((c ^ (lr & 15)) * 8)]) = g[i];
      }
      if (t < 128) ts[buf ^ 1][t] = gtv;
    }
    __syncthreads();
    buf ^= 1;
  }

  #pragma unroll
  for (int f = 0; f < 4; f++)
    #pragma unroll
    for (int i = 0; i < 4; i++) {
      float v = acc[f][i];
      v += __shfl_xor(v, 1); v += __shfl_xor(v, 2);
      v += __shfl_xor(v, 4); v += __shfl_xor(v, 8);
      acc[f][i] = v;
    }
  int f = c16 >> 2, i = c16 & 3;
  int row = mw * 64 + f * 16 + quad * 4 + i;
  atomicAdd(&lsum[row], acc[f][i]);
}

// ---------------- K8: final reduction ----------------
__global__ void __launch_bounds__(1024) k_final(const float* __restrict__ lsum,
    const float* __restrict__ corr, float* __restrict__ out) {
  __shared__ double red[1024];
  int t = threadIdx.x;
  double s = 0.0;
  for (int r = t; r < NROWS; r += 1024) {
    double v = (double)lsum[r] - (double)corr[r];
    s += 10.0 + log(v);
  }
  red[t] = s; __syncthreads();
  for (int d = 512; d > 0; d >>= 1) { if (t < d) red[t] += red[t + d]; __syncthreads(); }
  if (t == 0) out[0] = (float)(red[0] / (double)NB);
}

extern "C" void kernel_launch(void* const* d_in, const int* in_sizes, int n_in,
                              void* d_out, int out_size, void* d_ws, size_t ws_size,
                              hipStream_t stream) {
  (void)in_sizes; (void)n_in; (void)out_size; (void)ws_size;
  const int* tp    = (const int*)d_in[0];
  const int* adj   = (const int*)d_in[1];
  const float* emb = (const float*)d_in[2];
  const int* rows = adj;
  const int* cols = adj + NE;

  char* ws = (char*)d_ws;
  size_t o = 0;
  auto alloc = [&](size_t bytes) -> char* {
    char* p = ws + o;
    o = (o + bytes + 255) & ~(size_t)255;
    return p;
  };
  // zero-initialized region (single memset)
  int* deg       = (int*)alloc(NODE * 4);
  double* Fsum   = (double*)alloc(128 * 8);
  double* Hsum   = (double*)alloc(128 * 8);
  double* S12    = (double*)alloc(2 * 8);
  float* lsum    = (float*)alloc(NROWS * 4);
  size_t zero_bytes = o;
  // rest
  float* G       = (float*)alloc(128 * 128 * 4);
  float* Gpart   = (float*)alloc((size_t)NSBLK * 16384 * 4);
  int* off       = (int*)alloc((NODE + 1) * 4);
  float* sqn     = (float*)alloc(NODE * 4);
  float* tsqn    = (float*)alloc((size_t)NODE_P * 4);
  float* coefA   = (float*)alloc(NROWS * 4);
  float* coefG   = (float*)alloc(NROWS * 4);
  float* corr    = (float*)alloc(NROWS * 4);
  int* colidx    = (int*)alloc((size_t)NE * 4);
  int* epos      = (int*)alloc((size_t)NE * 4);
  unsigned short* featb = (unsigned short*)alloc((size_t)NODE_P * HID * 2);
  unsigned short* embb  = (unsigned short*)alloc((size_t)NODE * HID * 2);

  hipMemsetAsync(d_ws, 0, zero_bytes, stream);
  k_prep<<<3750 + (NE + 255) / 256, 256, 0, stream>>>(emb, embb, rows, deg, epos);
  k_scan<<<1, 1024, 0, stream>>>(deg, off);
  k_scatter<<<(NE + 255) / 256, 256, 0, stream>>>(rows, cols, off, epos, colidx);
  k_aggregate<<<NODE_P / 4, 256, 0, stream>>>(embb, off, colidx, featb, sqn, tsqn);
  k_nodestats<<<NSBLK, 256, 0, stream>>>(featb, sqn, Gpart, Fsum, Hsum, S12);
  k_greduce<<<64, 256, 0, stream>>>(Gpart, G);
  k_pairstats<<<NB / 8, 512, 0, stream>>>(tp, featb, sqn, G, Fsum, Hsum, S12, coefA, coefG, corr);
  k_fused<<<NCHUNK * 32, 256, 0, stream>>>(tp, featb, tsqn, coefA, coefG, lsum);
  k_final<<<1, 1024, 0, stream>>>(lsum, corr, (float*)d_out);
}

// Round 15
// 305.497 us; speedup vs baseline: 1.1756x; 1.0089x over previous
//
#include <hip/hip_runtime.h>

#define NODE 30000
#define NODE_P 30080   // padded to 235*128
#define HID 128
#define NE 600000
#define NB 4096
#define NROWS 8192
#define NSBLK 235      // nodestats blocks (128 nodes each)
#define NCHUNK 16      // k_fused node chunks
#define NRND 235       // k_fused rounds of 128 nodes over NODE_P
#define DCAP 96        // padded adjacency capacity (Poisson(20): P(deg>=96) ~ 1e-36)

typedef short bf16x8 __attribute__((ext_vector_type(8)));
typedef float f32x4 __attribute__((ext_vector_type(4)));
typedef unsigned short u16x8 __attribute__((ext_vector_type(8)));

__device__ __forceinline__ unsigned short f2bf(float x) {
  union { float f; unsigned u; } v; v.f = x;
  unsigned r = v.u + 0x7fffu + ((v.u >> 16) & 1u);
  return (unsigned short)(r >> 16);
}
__device__ __forceinline__ float bf2f(unsigned short h) {
  union { unsigned u; float f; } v; v.u = ((unsigned)h) << 16; return v.f;
}
__device__ __forceinline__ float fast_exp2(float x) {
#if __has_builtin(__builtin_amdgcn_exp2f)
  return __builtin_amdgcn_exp2f(x);
#else
  return exp2f(x);
#endif
}

// ---------------- K1: cast emb->bf16 (blocks 0..3749) + direct padded-adjacency scatter ----------------
__global__ void k_prep(const float* __restrict__ emb, unsigned short* __restrict__ embb,
                       const int* __restrict__ rows, const int* __restrict__ cols,
                       int* __restrict__ deg, int* __restrict__ padcol) {
  int b = blockIdx.x;
  if (b < 3750) {
    int i = (b * 256 + threadIdx.x) * 4;   // covers 3.84M exactly
    float4 v = *(const float4*)(emb + i);
    ushort4 o;
    o.x = f2bf(v.x); o.y = f2bf(v.y); o.z = f2bf(v.z); o.w = f2bf(v.w);
    *(ushort4*)(embb + i) = o;
  } else {
    int e = (b - 3750) * 256 + threadIdx.x;
    if (e < NE) {
      int r = rows[e];
      int p = atomicAdd(&deg[r], 1);       // slot within row r
      padcol[r * DCAP + p] = cols[e];      // no CSR scan/scatter needed
    }
  }
}

// ---------------- K4: per-row aggregation (1 wave = 1 row; 8-deep main, predicated 4-deep tail) ----------------
__global__ void __launch_bounds__(256) k_aggregate(const unsigned short* __restrict__ embb,
    const int* __restrict__ deg, const int* __restrict__ padcol,
    unsigned short* __restrict__ featb, float* __restrict__ sqn,
    float* __restrict__ tsqn) {
  int wv = threadIdx.x >> 6, lane = threadIdx.x & 63;
  int r = blockIdx.x * 4 + wv;
  if (r >= NODE) {             // pad rows NODE..NODE_P-1
    ushort2 z; z.x = 0; z.y = 0;
    *(ushort2*)(featb + (size_t)r * HID + lane * 2) = z;
    if (lane == 0) tsqn[r] = -1e30f;
    return;
  }
  const int* cix = padcol + r * DCAP;
  int dg = deg[r];
  float a0 = 0.f, a1 = 0.f, b0 = 0.f, b1 = 0.f;
  float c0a = 0.f, c1a = 0.f, d0 = 0.f, d1 = 0.f;
  int e = 0;
  for (; e + 7 < dg; e += 8) {
    int n0 = cix[e],     n1 = cix[e + 1], n2 = cix[e + 2], n3 = cix[e + 3];
    int n4 = cix[e + 4], n5 = cix[e + 5], n6 = cix[e + 6], n7 = cix[e + 7];
    ushort2 v0 = *(const ushort2*)(embb + (size_t)n0 * HID + lane * 2);
    ushort2 v1 = *(const ushort2*)(embb + (size_t)n1 * HID + lane * 2);
    ushort2 v2 = *(const ushort2*)(embb + (size_t)n2 * HID + lane * 2);
    ushort2 v3 = *(const ushort2*)(embb + (size_t)n3 * HID + lane * 2);
    ushort2 v4 = *(const ushort2*)(embb + (size_t)n4 * HID + lane * 2);
    ushort2 v5 = *(const ushort2*)(embb + (size_t)n5 * HID + lane * 2);
    ushort2 v6 = *(const ushort2*)(embb + (size_t)n6 * HID + lane * 2);
    ushort2 v7 = *(const ushort2*)(embb + (size_t)n7 * HID + lane * 2);
    a0 += bf2f(v0.x) + bf2f(v4.x); a1 += bf2f(v0.y) + bf2f(v4.y);
    b0 += bf2f(v1.x) + bf2f(v5.x); b1 += bf2f(v1.y) + bf2f(v5.y);
    c0a += bf2f(v2.x) + bf2f(v6.x); c1a += bf2f(v2.y) + bf2f(v6.y);
    d0 += bf2f(v3.x) + bf2f(v7.x); d1 += bf2f(v3.y) + bf2f(v7.y);
  }
  for (; e < dg; e += 4) {
    bool m1 = (e + 1 < dg), m2 = (e + 2 < dg), m3 = (e + 3 < dg);
    int n0 = cix[e];
    int n1 = cix[m1 ? e + 1 : e];
    int n2 = cix[m2 ? e + 2 : e];
    int n3 = cix[m3 ? e + 3 : e];
    ushort2 v0 = *(const ushort2*)(embb + (size_t)n0 * HID + lane * 2);
    ushort2 v1 = *(const ushort2*)(embb + (size_t)n1 * HID + lane * 2);
    ushort2 v2 = *(const ushort2*)(embb + (size_t)n2 * HID + lane * 2);
    ushort2 v3 = *(const ushort2*)(embb + (size_t)n3 * HID + lane * 2);
    a0 += bf2f(v0.x);                  a1 += bf2f(v0.y);
    b0 += m1 ? bf2f(v1.x) : 0.f;       b1 += m1 ? bf2f(v1.y) : 0.f;
    c0a += m2 ? bf2f(v2.x) : 0.f;      c1a += m2 ? bf2f(v2.y) : 0.f;
    d0 += m3 ? bf2f(v3.x) : 0.f;       d1 += m3 ? bf2f(v3.y) : 0.f;
  }
  a0 += b0 + c0a + d0; a1 += b1 + c1a + d1;
  float w = 1.0f / (float)(dg > 0 ? dg : 1);
  a0 *= w; a1 *= w;
  ushort2 hb; hb.x = f2bf(a0); hb.y = f2bf(a1);
  *(ushort2*)(featb + (size_t)r * HID + lane * 2) = hb;
  float q0 = bf2f(hb.x), q1 = bf2f(hb.y);
  float ss = q0 * q0 + q1 * q1;
  for (int m = 1; m < 64; m <<= 1) ss += __shfl_xor(ss, m);
  if (lane == 0) { sqn[r] = ss; tsqn[r] = -0.5f * ss; }
}

// ---------------- K5: node stats: Gram partials (no atomics) + Fsum/Hsum/S1/S2 ----------------
__global__ void __launch_bounds__(256) k_nodestats(const unsigned short* __restrict__ featb,
    const float* __restrict__ sqn, float* __restrict__ Gpart,
    double* __restrict__ Fsum, double* __restrict__ Hsum, double* __restrict__ S12) {
  __shared__ unsigned short lds[128 * 136];
  __shared__ double red[256];
  int t = threadIdx.x;
  int n0 = blockIdx.x * 128;
  {
    int n = t >> 1, h = t & 1;
    unsigned short* dst = lds + n * 136 + h * 64;
    if (n0 + n < NODE) {
      const unsigned short* src = featb + (size_t)(n0 + n) * HID + h * 64;
      #pragma unroll
      for (int i = 0; i < 64; i += 8) *(u16x8*)(dst + i) = *(const u16x8*)(src + i);
    } else {
      u16x8 z = {0, 0, 0, 0, 0, 0, 0, 0};
      #pragma unroll
      for (int i = 0; i < 64; i += 8) *(u16x8*)(dst + i) = z;
    }
  }
  __syncthreads();
  int i0 = (t >> 4) * 8, j0 = (t & 15) * 8;
  float acc[8][8];
  #pragma unroll
  for (int i = 0; i < 8; i++)
    #pragma unroll
    for (int j = 0; j < 8; j++) acc[i][j] = 0.f;
  for (int r = 0; r < 128; r++) {
    const unsigned short* row = lds + r * 136;
    u16x8 va = *(const u16x8*)(row + i0);
    u16x8 vb = *(const u16x8*)(row + j0);
    float ai[8], aj[8];
    #pragma unroll
    for (int k = 0; k < 8; k++) { ai[k] = bf2f(va[k]); aj[k] = bf2f(vb[k]); }
    #pragma unroll
    for (int i = 0; i < 8; i++)
      #pragma unroll
      for (int j = 0; j < 8; j++) acc[i][j] = fmaf(ai[i], aj[j], acc[i][j]);
  }
  float* gp = Gpart + (size_t)blockIdx.x * 16384;
  #pragma unroll
  for (int i = 0; i < 8; i++) {
    f32x4 v0, v1;
    #pragma unroll
    for (int j = 0; j < 4; j++) { v0[j] = acc[i][j]; v1[j] = acc[i][4 + j]; }
    *(f32x4*)(gp + (i0 + i) * 128 + j0) = v0;
    *(f32x4*)(gp + (i0 + i) * 128 + j0 + 4) = v1;
  }
  int d = t & 127, hh = t >> 7;
  double fs = 0.0, hs = 0.0, s1 = 0.0, s2 = 0.0;
  for (int n = hh * 64; n < hh * 64 + 64; n++) {
    int gn = n0 + n;
    if (gn >= NODE) break;
    float v = bf2f(lds[n * 136 + d]);
    float q = sqn[gn];
    fs += (double)v;
    hs += (double)q * (double)v;
    if (d == 0) { s1 += (double)q; s2 += (double)q * (double)q; }
  }
  red[t] = fs; __syncthreads();
  if (hh == 0) atomicAdd(&Fsum[d], red[t] + red[t + 128]);
  __syncthreads();
  red[t] = hs; __syncthreads();
  if (hh == 0) atomicAdd(&Hsum[d], red[t] + red[t + 128]);
  if (t == 0) { atomicAdd(&S12[0], s1); atomicAdd(&S12[1], s2); }
  if (t == 128) { atomicAdd(&S12[0], s1); atomicAdd(&S12[1], s2); }
}

// ---------------- K5b: reduce Gram partials (64 blocks, coalesced) ----------------
__global__ void __launch_bounds__(256) k_greduce(const float* __restrict__ Gpart,
                                                 float* __restrict__ G) {
  int idx = blockIdx.x * 256 + threadIdx.x;   // 64 blocks cover 16384
  float s = 0.f;
  for (int b = 0; b < NSBLK; b++)
    s += Gpart[(size_t)b * 16384 + idx];
  G[idx] = s;
}

// ---------------- K6: per-pair coeffs (f64), 8 pairs/block (512 thr), G staged in LDS ----------------
__global__ void __launch_bounds__(512) k_pairstats(const int* __restrict__ tp,
    const unsigned short* __restrict__ featb, const float* __restrict__ sqn,
    const float* __restrict__ G, const double* __restrict__ Fsum,
    const double* __restrict__ Hsum, const double* __restrict__ S12,
    float* __restrict__ coefA, float* __restrict__ coefG, float* __restrict__ corr) {
  __shared__ float Gs[128 * 128];            // 64 KB — read G once per block
  __shared__ float shl[8][128], shr[8][128];
  int t = threadIdx.x;
  for (int i = t * 4; i < 16384; i += 2048)
    *(f32x4*)(Gs + i) = *(const f32x4*)(G + i);
  int wv = t >> 6, lane = t & 63;
  int b = blockIdx.x * 8 + wv;
  int l = tp[2 * b], r = tp[2 * b + 1];
  ushort2 lu = *(const ushort2*)(featb + (size_t)l * HID + lane * 2);
  ushort2 ru = *(const ushort2*)(featb + (size_t)r * HID + lane * 2);
  float2 lv, rv;
  lv.x = bf2f(lu.x); lv.y = bf2f(lu.y);
  rv.x = bf2f(ru.x); rv.y = bf2f(ru.y);
  shl[wv][lane * 2] = lv.x; shl[wv][lane * 2 + 1] = lv.y;
  shr[wv][lane * 2] = rv.x; shr[wv][lane * 2 + 1] = rv.y;
  __syncthreads();
  float dx = lv.x - rv.x, dy = lv.y - rv.y;
  float ps = dx * dx + dy * dy;
  for (int m = 1; m < 64; m <<= 1) ps += __shfl_xor(ps, m);
  double ql0 = 0, ql1 = 0, qr0 = 0, qr1 = 0;
  for (int j = 0; j < 128; j++) {
    float2 g = *(const float2*)(Gs + j * 128 + lane * 2);
    double slj = (double)shl[wv][j], srj = (double)shr[wv][j];
    ql0 += (double)g.x * slj; ql1 += (double)g.y * slj;
    qr0 += (double)g.x * srj; qr1 += (double)g.y * srj;
  }
  double lx0 = lv.x, lx1 = lv.y, rx0 = rv.x, rx1 = rv.y;
  double lG = lx0 * ql0 + lx1 * ql1;
  double rG = rx0 * qr0 + rx1 * qr1;
  double f0 = Fsum[lane * 2], f1 = Fsum[lane * 2 + 1];
  double h0 = Hsum[lane * 2], h1 = Hsum[lane * 2 + 1];
  double lF = lx0 * f0 + lx1 * f1, rF = rx0 * f0 + rx1 * f1;
  double lH = lx0 * h0 + lx1 * h1, rH = rx0 * h0 + rx1 * h1;
  for (int m = 1; m < 64; m <<= 1) {
    lG += __shfl_xor(lG, m); rG += __shfl_xor(rG, m);
    lF += __shfl_xor(lF, m); rF += __shfl_xor(rF, m);
    lH += __shfl_xor(lH, m); rH += __shfl_xor(rH, m);
  }
  if (lane == 0) {
    const double GAM = 3.0, LAM = 30.0, L2E = 1.4426950408889634;
    double pos = (double)ps;
    double S1 = S12[0], S2 = S12[1];
    double sl = (double)sqn[l], sr = (double)sqn[r];
    double N = (double)NODE;
    for (int side = 0; side < 2; side++) {
      double u  = pos + GAM - (side ? sr : sl);
      double F  = side ? rF : lF;
      double Gq = side ? rG : lG;
      double H  = side ? rH : lH;
      double Sx  = N * u - S1 + 2.0 * F;
      double Sxx = N * u * u + S2 + 4.0 * Gq - 2.0 * u * S1 + 4.0 * u * F - 4.0 * H;
      double xl = pos + GAM;
      double xr2 = GAM;
      double Sxm, Sxxm;
      if (l != r) { Sxm = Sx - xl - xr2; Sxxm = Sxx - xl * xl - xr2 * xr2; }
      else        { Sxm = Sx - 2.0 * GAM; Sxxm = Sxx; }
      double mn = Sxm / N;
      double var = Sxxm / N - mn * mn;
      double sd = sqrt(var);
      double alpha = 2.0 * LAM / sd;
      double g2 = LAM * (u - mn) / sd;
      double cr;
      if (l != r)
        cr = exp(LAM * (xl - mn) / sd) + exp(LAM * (GAM - mn) / sd)
             - 2.0 * exp(LAM * (0.0 - mn) / sd);
      else
        cr = exp(LAM * (GAM - mn) / sd) - exp(LAM * (-GAM - mn) / sd);
      int row = b + side * NB;
      coefA[row] = (float)(alpha * L2E);
      coefG[row] = (float)(g2 * L2E);
      corr[row]  = (float)cr;
    }
  }
}

// ---------------- K7: fused bf16-MFMA GEMM + exp-sum (measured-best config, unchanged) ----------------
__global__ void __launch_bounds__(256, 2) k_fused(const int* __restrict__ tp,
    const unsigned short* __restrict__ featb, const float* __restrict__ tsqn,
    const float* __restrict__ coefA, const float* __restrict__ coefG,
    float* __restrict__ lsum) {
  __shared__ unsigned short bt[2][128 * 128];   // [buf][row*128 + phys_chunk*8]
  __shared__ float ts[2][128];
  int t = threadIdx.x;
  int wv = t >> 6, lane = t & 63;
  int chunk = blockIdx.x >> 5;    // 0..15 (consecutive blocks share chunk)
  int rg = blockIdx.x & 31;       // 0..31
  int mw = rg * 4 + wv;           // 0..127, 64 rows each
  int quad = lane >> 4, c16 = lane & 15;

  bf16x8 af[4][4];
  float cA[4][4], cG[4][4];
  #pragma unroll
  for (int f = 0; f < 4; f++) {
    int row = mw * 64 + f * 16 + c16;
    int node = (row < NB) ? tp[2 * row] : tp[2 * (row - NB) + 1];
    const unsigned short* src = featb + (size_t)node * HID + quad * 8;
    #pragma unroll
    for (int kc = 0; kc < 4; kc++)
      af[f][kc] = *(const bf16x8*)(src + kc * 32);
    int cr0 = mw * 64 + f * 16 + quad * 4;
    #pragma unroll
    for (int i = 0; i < 4; i++) { cA[f][i] = coefA[cr0 + i]; cG[f][i] = coefG[cr0 + i]; }
  }
  float acc[4][4];
  #pragma unroll
  for (int f = 0; f < 4; f++)
    #pragma unroll
    for (int i = 0; i < 4; i++) acc[f][i] = 0.f;

  int r0 = (NRND * chunk) / NCHUNK, r1 = (NRND * (chunk + 1)) / NCHUNK;

  u16x8 g[8];
  float gtv = 0.f;
  {
    int n0 = r0 * 128;
    #pragma unroll
    for (int i = 0; i < 8; i++) {
      int gi = i * 256 + t, lr = gi >> 4, c = gi & 15;
      g[i] = *(const u16x8*)(featb + (size_t)(n0 + lr) * HID + c * 8);
    }
    if (t < 128) gtv = tsqn[n0 + t];
  }
  #pragma unroll
  for (int i = 0; i < 8; i++) {
    int gi = i * 256 + t, lr = gi >> 4, c = gi & 15;
    *(u16x8*)(&bt[0][lr * 128 + ((c ^ (lr & 15)) * 8)]) = g[i];
  }
  if (t < 128) ts[0][t] = gtv;
  __syncthreads();

  int buf = 0;
  for (int r = r0; r < r1; r++) {
    if (r + 1 < r1) {               // issue next round's global loads
      int n0 = (r + 1) * 128;
      #pragma unroll
      for (int i = 0; i < 8; i++) {
        int gi = i * 256 + t, lr = gi >> 4, c = gi & 15;
        g[i] = *(const u16x8*)(featb + (size_t)(n0 + lr) * HID + c * 8);
      }
      if (t < 128) gtv = tsqn[n0 + t];
    }
    #pragma unroll 2
    for (int s = 0; s < 8; s++) {
      int lr = s * 16 + c16;
      const unsigned short* base = &bt[buf][lr * 128];
      bf16x8 b0 = *(const bf16x8*)(base + (((0 * 4 + quad) ^ c16) * 8));
      bf16x8 b1 = *(const bf16x8*)(base + (((1 * 4 + quad) ^ c16) * 8));
      bf16x8 b2 = *(const bf16x8*)(base + (((2 * 4 + quad) ^ c16) * 8));
      bf16x8 b3 = *(const bf16x8*)(base + (((3 * 4 + quad) ^ c16) * 8));
      float tsq = ts[buf][s * 16 + c16];
      #pragma unroll
      for (int f = 0; f < 4; f++) {
        f32x4 c = {tsq, tsq, tsq, tsq};   // seed: D = S + tsq from the MFMA
        c = __builtin_amdgcn_mfma_f32_16x16x32_bf16(af[f][0], b0, c, 0, 0, 0);
        c = __builtin_amdgcn_mfma_f32_16x16x32_bf16(af[f][1], b1, c, 0, 0, 0);
        c = __builtin_amdgcn_mfma_f32_16x16x32_bf16(af[f][2], b2, c, 0, 0, 0);
        c = __builtin_amdgcn_mfma_f32_16x16x32_bf16(af[f][3], b3, c, 0, 0, 0);
        #pragma unroll
        for (int i = 0; i < 4; i++)
          acc[f][i] += fast_exp2(fmaf(cA[f][i], c[i], cG[f][i]));
      }
    }
    if (r + 1 < r1) {               // write next round into other buffer
      #pragma unroll
      for (int i = 0; i < 8; i++) {
        int gi = i * 256 + t, lr = gi >> 4, c = gi & 15;
        *(u16x8*)(&bt[buf ^ 1][lr * 128 + ((c ^ (lr & 15)) * 8)]) = g[i];
      }
      if (t < 128) ts[buf ^ 1][t] = gtv;
    }
    __syncthreads();
    buf ^= 1;
  }

  #pragma unroll
  for (int f = 0; f < 4; f++)
    #pragma unroll
    for (int i = 0; i < 4; i++) {
      float v = acc[f][i];
      v += __shfl_xor(v, 1); v += __shfl_xor(v, 2);
      v += __shfl_xor(v, 4); v += __shfl_xor(v, 8);
      acc[f][i] = v;
    }
  int f = c16 >> 2, i = c16 & 3;
  int row = mw * 64 + f * 16 + quad * 4 + i;
  atomicAdd(&lsum[row], acc[f][i]);
}

// ---------------- K8: final reduction ----------------
__global__ void __launch_bounds__(1024) k_final(const float* __restrict__ lsum,
    const float* __restrict__ corr, float* __restrict__ out) {
  __shared__ double red[1024];
  int t = threadIdx.x;
  double s = 0.0;
  for (int r = t; r < NROWS; r += 1024) {
    double v = (double)lsum[r] - (double)corr[r];
    s += 10.0 + log(v);
  }
  red[t] = s; __syncthreads();
  for (int d = 512; d > 0; d >>= 1) { if (t < d) red[t] += red[t + d]; __syncthreads(); }
  if (t == 0) out[0] = (float)(red[0] / (double)NB);
}

extern "C" void kernel_launch(void* const* d_in, const int* in_sizes, int n_in,
                              void* d_out, int out_size, void* d_ws, size_t ws_size,
                              hipStream_t stream) {
  (void)in_sizes; (void)n_in; (void)out_size; (void)ws_size;
  const int* tp    = (const int*)d_in[0];
  const int* adj   = (const int*)d_in[1];
  const float* emb = (const float*)d_in[2];
  const int* rows = adj;
  const int* cols = adj + NE;

  char* ws = (char*)d_ws;
  size_t o = 0;
  auto alloc = [&](size_t bytes) -> char* {
    char* p = ws + o;
    o = (o + bytes + 255) & ~(size_t)255;
    return p;
  };
  // zero-initialized region (single memset)
  int* deg       = (int*)alloc(NODE * 4);
  double* Fsum   = (double*)alloc(128 * 8);
  double* Hsum   = (double*)alloc(128 * 8);
  double* S12    = (double*)alloc(2 * 8);
  float* lsum    = (float*)alloc(NROWS * 4);
  size_t zero_bytes = o;
  // rest
  float* G       = (float*)alloc(128 * 128 * 4);
  float* Gpart   = (float*)alloc((size_t)NSBLK * 16384 * 4);
  float* sqn     = (float*)alloc(NODE * 4);
  float* tsqn    = (float*)alloc((size_t)NODE_P * 4);
  float* coefA   = (float*)alloc(NROWS * 4);
  float* coefG   = (float*)alloc(NROWS * 4);
  float* corr    = (float*)alloc(NROWS * 4);
  int* padcol    = (int*)alloc((size_t)NODE * DCAP * 4);
  unsigned short* featb = (unsigned short*)alloc((size_t)NODE_P * HID * 2);
  unsigned short* embb  = (unsigned short*)alloc((size_t)NODE * HID * 2);

  hipMemsetAsync(d_ws, 0, zero_bytes, stream);
  k_prep<<<3750 + (NE + 255) / 256, 256, 0, stream>>>(emb, embb, rows, cols, deg, padcol);
  k_aggregate<<<NODE_P / 4, 256, 0, stream>>>(embb, deg, padcol, featb, sqn, tsqn);
  k_nodestats<<<NSBLK, 256, 0, stream>>>(featb, sqn, Gpart, Fsum, Hsum, S12);
  k_greduce<<<64, 256, 0, stream>>>(Gpart, G);
  k_pairstats<<<NB / 8, 512, 0, stream>>>(tp, featb, sqn, G, Fsum, Hsum, S12, coefA, coefG, corr);
  k_fused<<<NCHUNK * 32, 256, 0, stream>>>(tp, featb, tsqn, coefA, coefG, lsum);
  k_final<<<1, 1024, 0, stream>>>(lsum, corr, (float*)d_out);
}

// Round 16
// 291.338 us; speedup vs baseline: 1.2327x; 1.0486x over previous
//
#include <hip/hip_runtime.h>

#define NODE 30000
#define NODE_P 30080   // padded to 235*128
#define HID 128
#define NE 600000
#define NB 4096
#define NROWS 8192
#define NSBLK 235      // nodestats blocks (128 nodes each)
#define NCHUNK 16      // k_fused node chunks
#define NRND 235       // k_fused rounds of 128 nodes over NODE_P
#define DCAP 96        // padded adjacency capacity (Poisson(20): P(deg>=96) ~ 1e-36)

typedef short bf16x8 __attribute__((ext_vector_type(8)));
typedef float f32x4 __attribute__((ext_vector_type(4)));
typedef unsigned short u16x8 __attribute__((ext_vector_type(8)));

__device__ __forceinline__ unsigned short f2bf(float x) {
  union { float f; unsigned u; } v; v.f = x;
  unsigned r = v.u + 0x7fffu + ((v.u >> 16) & 1u);
  return (unsigned short)(r >> 16);
}
__device__ __forceinline__ float bf2f(unsigned short h) {
  union { unsigned u; float f; } v; v.u = ((unsigned)h) << 16; return v.f;
}
__device__ __forceinline__ float fast_exp2(float x) {
#if __has_builtin(__builtin_amdgcn_exp2f)
  return __builtin_amdgcn_exp2f(x);
#else
  return exp2f(x);
#endif
}

// ---------------- K1: cast emb->bf16 (blocks 0..3749) + direct padded-adjacency scatter ----------------
__global__ void k_prep(const float* __restrict__ emb, unsigned short* __restrict__ embb,
                       const int* __restrict__ rows, const int* __restrict__ cols,
                       int* __restrict__ deg, int* __restrict__ padcol) {
  int b = blockIdx.x;
  if (b < 3750) {
    int i = (b * 256 + threadIdx.x) * 4;   // covers 3.84M exactly
    float4 v = *(const float4*)(emb + i);
    ushort4 o;
    o.x = f2bf(v.x); o.y = f2bf(v.y); o.z = f2bf(v.z); o.w = f2bf(v.w);
    *(ushort4*)(embb + i) = o;
  } else {
    int e = (b - 3750) * 256 + threadIdx.x;
    if (e < NE) {
      int r = rows[e];
      int p = atomicAdd(&deg[r], 1);       // slot within row r
      padcol[r * DCAP + p] = cols[e];      // no CSR scan/scatter needed
    }
  }
}

// ---------------- K4: per-row aggregation (1 wave = 1 row; half-wave ushort4 gather, 2 edges/instr) ----------------
__global__ void __launch_bounds__(256) k_aggregate(const unsigned short* __restrict__ embb,
    const int* __restrict__ deg, const int* __restrict__ padcol,
    unsigned short* __restrict__ featb, float* __restrict__ sqn,
    float* __restrict__ tsqn) {
  int wv = threadIdx.x >> 6, lane = threadIdx.x & 63;
  int r = blockIdx.x * 4 + wv;
  if (r >= NODE) {             // pad rows NODE..NODE_P-1
    ushort2 z; z.x = 0; z.y = 0;
    *(ushort2*)(featb + (size_t)r * HID + lane * 2) = z;
    if (lane == 0) tsqn[r] = -1e30f;
    return;
  }
  const int* cix = padcol + r * DCAP;
  int dg = deg[r];
  int h = lane >> 5, sl = lane & 31;     // lanes 0-31: even edges, 32-63: odd edges
  float a0 = 0.f, a1 = 0.f, a2 = 0.f, a3 = 0.f;
  float b0 = 0.f, b1 = 0.f, b2 = 0.f, b3 = 0.f;
  float c0 = 0.f, c1 = 0.f, c2 = 0.f, c3 = 0.f;
  float d0 = 0.f, d1 = 0.f, d2 = 0.f, d3 = 0.f;
  int e = 0;
  for (; e + 7 < dg; e += 8) {           // 4 paired loads in flight (8 edges)
    int m0 = cix[e + h];
    int m1 = cix[e + 2 + h];
    int m2 = cix[e + 4 + h];
    int m3 = cix[e + 6 + h];
    ushort4 w0 = *(const ushort4*)(embb + (size_t)m0 * HID + sl * 4);
    ushort4 w1 = *(const ushort4*)(embb + (size_t)m1 * HID + sl * 4);
    ushort4 w2 = *(const ushort4*)(embb + (size_t)m2 * HID + sl * 4);
    ushort4 w3 = *(const ushort4*)(embb + (size_t)m3 * HID + sl * 4);
    a0 += bf2f(w0.x); a1 += bf2f(w0.y); a2 += bf2f(w0.z); a3 += bf2f(w0.w);
    b0 += bf2f(w1.x); b1 += bf2f(w1.y); b2 += bf2f(w1.z); b3 += bf2f(w1.w);
    c0 += bf2f(w2.x); c1 += bf2f(w2.y); c2 += bf2f(w2.z); c3 += bf2f(w2.w);
    d0 += bf2f(w3.x); d1 += bf2f(w3.y); d2 += bf2f(w3.z); d3 += bf2f(w3.w);
  }
  for (; e < dg; e += 2) {               // predicated paired tail
    bool mh = (e + h) < dg;
    int mm = cix[mh ? e + h : e];
    ushort4 w = *(const ushort4*)(embb + (size_t)mm * HID + sl * 4);
    a0 += mh ? bf2f(w.x) : 0.f; a1 += mh ? bf2f(w.y) : 0.f;
    a2 += mh ? bf2f(w.z) : 0.f; a3 += mh ? bf2f(w.w) : 0.f;
  }
  a0 += b0 + c0 + d0; a1 += b1 + c1 + d1;
  a2 += b2 + c2 + d2; a3 += b3 + c3 + d3;
  // combine even/odd halves (lane i <-> lane 32+i hold same dims)
  a0 += __shfl_xor(a0, 32); a1 += __shfl_xor(a1, 32);
  a2 += __shfl_xor(a2, 32); a3 += __shfl_xor(a3, 32);
  float w = 1.0f / (float)(dg > 0 ? dg : 1);
  a0 *= w; a1 *= w; a2 *= w; a3 *= w;
  ushort4 hb; hb.x = f2bf(a0); hb.y = f2bf(a1); hb.z = f2bf(a2); hb.w = f2bf(a3);
  if (h == 0) *(ushort4*)(featb + (size_t)r * HID + sl * 4) = hb;
  float q0 = bf2f(hb.x), q1 = bf2f(hb.y), q2 = bf2f(hb.z), q3 = bf2f(hb.w);
  float ss = q0 * q0 + q1 * q1 + q2 * q2 + q3 * q3;
  ss += __shfl_xor(ss, 1); ss += __shfl_xor(ss, 2); ss += __shfl_xor(ss, 4);
  ss += __shfl_xor(ss, 8); ss += __shfl_xor(ss, 16);
  if (lane == 0) { sqn[r] = ss; tsqn[r] = -0.5f * ss; }
}

// ---------------- K5: node stats: Gram partials (no atomics) + Fsum/Hsum/S1/S2 ----------------
__global__ void __launch_bounds__(256) k_nodestats(const unsigned short* __restrict__ featb,
    const float* __restrict__ sqn, float* __restrict__ Gpart,
    double* __restrict__ Fsum, double* __restrict__ Hsum, double* __restrict__ S12) {
  __shared__ unsigned short lds[128 * 136];
  __shared__ double red[256];
  int t = threadIdx.x;
  int n0 = blockIdx.x * 128;
  {
    int n = t >> 1, h = t & 1;
    unsigned short* dst = lds + n * 136 + h * 64;
    if (n0 + n < NODE) {
      const unsigned short* src = featb + (size_t)(n0 + n) * HID + h * 64;
      #pragma unroll
      for (int i = 0; i < 64; i += 8) *(u16x8*)(dst + i) = *(const u16x8*)(src + i);
    } else {
      u16x8 z = {0, 0, 0, 0, 0, 0, 0, 0};
      #pragma unroll
      for (int i = 0; i < 64; i += 8) *(u16x8*)(dst + i) = z;
    }
  }
  __syncthreads();
  int i0 = (t >> 4) * 8, j0 = (t & 15) * 8;
  float acc[8][8];
  #pragma unroll
  for (int i = 0; i < 8; i++)
    #pragma unroll
    for (int j = 0; j < 8; j++) acc[i][j] = 0.f;
  for (int r = 0; r < 128; r++) {
    const unsigned short* row = lds + r * 136;
    u16x8 va = *(const u16x8*)(row + i0);
    u16x8 vb = *(const u16x8*)(row + j0);
    float ai[8], aj[8];
    #pragma unroll
    for (int k = 0; k < 8; k++) { ai[k] = bf2f(va[k]); aj[k] = bf2f(vb[k]); }
    #pragma unroll
    for (int i = 0; i < 8; i++)
      #pragma unroll
      for (int j = 0; j < 8; j++) acc[i][j] = fmaf(ai[i], aj[j], acc[i][j]);
  }
  float* gp = Gpart + (size_t)blockIdx.x * 16384;
  #pragma unroll
  for (int i = 0; i < 8; i++) {
    f32x4 v0, v1;
    #pragma unroll
    for (int j = 0; j < 4; j++) { v0[j] = acc[i][j]; v1[j] = acc[i][4 + j]; }
    *(f32x4*)(gp + (i0 + i) * 128 + j0) = v0;
    *(f32x4*)(gp + (i0 + i) * 128 + j0 + 4) = v1;
  }
  int d = t & 127, hh = t >> 7;
  double fs = 0.0, hs = 0.0, s1 = 0.0, s2 = 0.0;
  for (int n = hh * 64; n < hh * 64 + 64; n++) {
    int gn = n0 + n;
    if (gn >= NODE) break;
    float v = bf2f(lds[n * 136 + d]);
    float q = sqn[gn];
    fs += (double)v;
    hs += (double)q * (double)v;
    if (d == 0) { s1 += (double)q; s2 += (double)q * (double)q; }
  }
  red[t] = fs; __syncthreads();
  if (hh == 0) atomicAdd(&Fsum[d], red[t] + red[t + 128]);
  __syncthreads();
  red[t] = hs; __syncthreads();
  if (hh == 0) atomicAdd(&Hsum[d], red[t] + red[t + 128]);
  if (t == 0) { atomicAdd(&S12[0], s1); atomicAdd(&S12[1], s2); }
  if (t == 128) { atomicAdd(&S12[0], s1); atomicAdd(&S12[1], s2); }
}

// ---------------- K5b: reduce Gram partials (64 blocks, coalesced) ----------------
__global__ void __launch_bounds__(256) k_greduce(const float* __restrict__ Gpart,
                                                 float* __restrict__ G) {
  int idx = blockIdx.x * 256 + threadIdx.x;   // 64 blocks cover 16384
  float s = 0.f;
  for (int b = 0; b < NSBLK; b++)
    s += Gpart[(size_t)b * 16384 + idx];
  G[idx] = s;
}

// ---------------- K6: per-pair coeffs (f64), 16 pairs/block (1024 thr), G staged in LDS ----------------
__global__ void __launch_bounds__(1024) k_pairstats(const int* __restrict__ tp,
    const unsigned short* __restrict__ featb, const float* __restrict__ sqn,
    const float* __restrict__ G, const double* __restrict__ Fsum,
    const double* __restrict__ Hsum, const double* __restrict__ S12,
    float* __restrict__ coefA, float* __restrict__ coefG, float* __restrict__ corr) {
  __shared__ float Gs[128 * 128];            // 64 KB — read G once per block
  __shared__ float shl[16][128], shr[16][128];
  int t = threadIdx.x;
  for (int i = t * 4; i < 16384; i += 4096)
    *(f32x4*)(Gs + i) = *(const f32x4*)(G + i);
  int wv = t >> 6, lane = t & 63;
  int b = blockIdx.x * 16 + wv;
  int l = tp[2 * b], r = tp[2 * b + 1];
  ushort2 lu = *(const ushort2*)(featb + (size_t)l * HID + lane * 2);
  ushort2 ru = *(const ushort2*)(featb + (size_t)r * HID + lane * 2);
  float2 lv, rv;
  lv.x = bf2f(lu.x); lv.y = bf2f(lu.y);
  rv.x = bf2f(ru.x); rv.y = bf2f(ru.y);
  shl[wv][lane * 2] = lv.x; shl[wv][lane * 2 + 1] = lv.y;
  shr[wv][lane * 2] = rv.x; shr[wv][lane * 2 + 1] = rv.y;
  __syncthreads();
  float dx = lv.x - rv.x, dy = lv.y - rv.y;
  float ps = dx * dx + dy * dy;
  for (int m = 1; m < 64; m <<= 1) ps += __shfl_xor(ps, m);
  double ql0 = 0, ql1 = 0, qr0 = 0, qr1 = 0;
  for (int j = 0; j < 128; j++) {
    float2 g = *(const float2*)(Gs + j * 128 + lane * 2);
    double slj = (double)shl[wv][j], srj = (double)shr[wv][j];
    ql0 += (double)g.x * slj; ql1 += (double)g.y * slj;
    qr0 += (double)g.x * srj; qr1 += (double)g.y * srj;
  }
  double lx0 = lv.x, lx1 = lv.y, rx0 = rv.x, rx1 = rv.y;
  double lG = lx0 * ql0 + lx1 * ql1;
  double rG = rx0 * qr0 + rx1 * qr1;
  double f0 = Fsum[lane * 2], f1 = Fsum[lane * 2 + 1];
  double h0 = Hsum[lane * 2], h1 = Hsum[lane * 2 + 1];
  double lF = lx0 * f0 + lx1 * f1, rF = rx0 * f0 + rx1 * f1;
  double lH = lx0 * h0 + lx1 * h1, rH = rx0 * h0 + rx1 * h1;
  for (int m = 1; m < 64; m <<= 1) {
    lG += __shfl_xor(lG, m); rG += __shfl_xor(rG, m);
    lF += __shfl_xor(lF, m); rF += __shfl_xor(rF, m);
    lH += __shfl_xor(lH, m); rH += __shfl_xor(rH, m);
  }
  if (lane == 0) {
    const double GAM = 3.0, LAM = 30.0, L2E = 1.4426950408889634;
    double pos = (double)ps;
    double S1 = S12[0], S2 = S12[1];
    double sl = (double)sqn[l], sr = (double)sqn[r];
    double N = (double)NODE;
    for (int side = 0; side < 2; side++) {
      double u  = pos + GAM - (side ? sr : sl);
      double F  = side ? rF : lF;
      double Gq = side ? rG : lG;
      double H  = side ? rH : lH;
      double Sx  = N * u - S1 + 2.0 * F;
      double Sxx = N * u * u + S2 + 4.0 * Gq - 2.0 * u * S1 + 4.0 * u * F - 4.0 * H;
      double xl = pos + GAM;
      double xr2 = GAM;
      double Sxm, Sxxm;
      if (l != r) { Sxm = Sx - xl - xr2; Sxxm = Sxx - xl * xl - xr2 * xr2; }
      else        { Sxm = Sx - 2.0 * GAM; Sxxm = Sxx; }
      double mn = Sxm / N;
      double var = Sxxm / N - mn * mn;
      double sd = sqrt(var);
      double alpha = 2.0 * LAM / sd;
      double g2 = LAM * (u - mn) / sd;
      double cr;
      if (l != r)
        cr = exp(LAM * (xl - mn) / sd) + exp(LAM * (GAM - mn) / sd)
             - 2.0 * exp(LAM * (0.0 - mn) / sd);
      else
        cr = exp(LAM * (GAM - mn) / sd) - exp(LAM * (-GAM - mn) / sd);
      int row = b + side * NB;
      coefA[row] = (float)(alpha * L2E);
      coefG[row] = (float)(g2 * L2E);
      corr[row]  = (float)cr;
    }
  }
}

// ---------------- K7: fused bf16-MFMA GEMM + exp-sum (measured-best config, unchanged) ----------------
__global__ void __launch_bounds__(256, 2) k_fused(const int* __restrict__ tp,
    const unsigned short* __restrict__ featb, const float* __restrict__ tsqn,
    const float* __restrict__ coefA, const float* __restrict__ coefG,
    float* __restrict__ lsum) {
  __shared__ unsigned short bt[2][128 * 128];   // [buf][row*128 + phys_chunk*8]
  __shared__ float ts[2][128];
  int t = threadIdx.x;
  int wv = t >> 6, lane = t & 63;
  int chunk = blockIdx.x >> 5;    // 0..15 (consecutive blocks share chunk)
  int rg = blockIdx.x & 31;       // 0..31
  int mw = rg * 4 + wv;           // 0..127, 64 rows each
  int quad = lane >> 4, c16 = lane & 15;

  bf16x8 af[4][4];
  float cA[4][4], cG[4][4];
  #pragma unroll
  for (int f = 0; f < 4; f++) {
    int row = mw * 64 + f * 16 + c16;
    int node = (row < NB) ? tp[2 * row] : tp[2 * (row - NB) + 1];
    const unsigned short* src = featb + (size_t)node * HID + quad * 8;
    #pragma unroll
    for (int kc = 0; kc < 4; kc++)
      af[f][kc] = *(const bf16x8*)(src + kc * 32);
    int cr0 = mw * 64 + f * 16 + quad * 4;
    #pragma unroll
    for (int i = 0; i < 4; i++) { cA[f][i] = coefA[cr0 + i]; cG[f][i] = coefG[cr0 + i]; }
  }
  float acc[4][4];
  #pragma unroll
  for (int f = 0; f < 4; f++)
    #pragma unroll
    for (int i = 0; i < 4; i++) acc[f][i] = 0.f;

  int r0 = (NRND * chunk) / NCHUNK, r1 = (NRND * (chunk + 1)) / NCHUNK;

  u16x8 g[8];
  float gtv = 0.f;
  {
    int n0 = r0 * 128;
    #pragma unroll
    for (int i = 0; i < 8; i++) {
      int gi = i * 256 + t, lr = gi >> 4, c = gi & 15;
      g[i] = *(const u16x8*)(featb + (size_t)(n0 + lr) * HID + c * 8);
    }
    if (t < 128) gtv = tsqn[n0 + t];
  }
  #pragma unroll
  for (int i = 0; i < 8; i++) {
    int gi = i * 256 + t, lr = gi >> 4, c = gi & 15;
    *(u16x8*)(&bt[0][lr * 128 + ((c ^ (lr & 15)) * 8)]) = g[i];
  }
  if (t < 128) ts[0][t] = gtv;
  __syncthreads();

  int buf = 0;
  for (int r = r0; r < r1; r++) {
    if (r + 1 < r1) {               // issue next round's global loads
      int n0 = (r + 1) * 128;
      #pragma unroll
      for (int i = 0; i < 8; i++) {
        int gi = i * 256 + t, lr = gi >> 4, c = gi & 15;
        g[i] = *(const u16x8*)(featb + (size_t)(n0 + lr) * HID + c * 8);
      }
      if (t < 128) gtv = tsqn[n0 + t];
    }
    #pragma unroll 2
    for (int s = 0; s < 8; s++) {
      int lr = s * 16 + c16;
      const unsigned short* base = &bt[buf][lr * 128];
      bf16x8 b0 = *(const bf16x8*)(base + (((0 * 4 + quad) ^ c16) * 8));
      bf16x8 b1 = *(const bf16x8*)(base + (((1 * 4 + quad) ^ c16) * 8));
      bf16x8 b2 = *(const bf16x8*)(base + (((2 * 4 + quad) ^ c16) * 8));
      bf16x8 b3 = *(const bf16x8*)(base + (((3 * 4 + quad) ^ c16) * 8));
      float tsq = ts[buf][s * 16 + c16];
      #pragma unroll
      for (int f = 0; f < 4; f++) {
        f32x4 c = {tsq, tsq, tsq, tsq};   // seed: D = S + tsq from the MFMA
        c = __builtin_amdgcn_mfma_f32_16x16x32_bf16(af[f][0], b0, c, 0, 0, 0);
        c = __builtin_amdgcn_mfma_f32_16x16x32_bf16(af[f][1], b1, c, 0, 0, 0);
        c = __builtin_amdgcn_mfma_f32_16x16x32_bf16(af[f][2], b2, c, 0, 0, 0);
        c = __builtin_amdgcn_mfma_f32_16x16x32_bf16(af[f][3], b3, c, 0, 0, 0);
        #pragma unroll
        for (int i = 0; i < 4; i++)
          acc[f][i] += fast_exp2(fmaf(cA[f][i], c[i], cG[f][i]));
      }
    }
    if (r + 1 < r1) {               // write next round into other buffer
      #pragma unroll
      for (int i = 0; i < 8; i++) {
        int gi = i * 256 + t, lr = gi >> 4, c = gi & 15;
        *(u16x8*)(&bt[buf ^ 1][lr * 128 + ((c ^ (lr & 15)) * 8)]) = g[i];
      }
      if (t < 128) ts[buf ^ 1][t] = gtv;
    }
    __syncthreads();
    buf ^= 1;
  }

  #pragma unroll
  for (int f = 0; f < 4; f++)
    #pragma unroll
    for (int i = 0; i < 4; i++) {
      float v = acc[f][i];
      v += __shfl_xor(v, 1); v += __shfl_xor(v, 2);
      v += __shfl_xor(v, 4); v += __shfl_xor(v, 8);
      acc[f][i] = v;
    }
  int f = c16 >> 2, i = c16 & 3;
  int row = mw * 64 + f * 16 + quad * 4 + i;
  atomicAdd(&lsum[row], acc[f][i]);
}

// ---------------- K8: final reduction ----------------
__global__ void __launch_bounds__(1024) k_final(const float* __restrict__ lsum,
    const float* __restrict__ corr, float* __restrict__ out) {
  __shared__ double red[1024];
  int t = threadIdx.x;
  double s = 0.0;
  for (int r = t; r < NROWS; r += 1024) {
    double v = (double)lsum[r] - (double)corr[r];
    s += 10.0 + log(v);
  }
  red[t] = s; __syncthreads();
  for (int d = 512; d > 0; d >>= 1) { if (t < d) red[t] += red[t + d]; __syncthreads(); }
  if (t == 0) out[0] = (float)(red[0] / (double)NB);
}

extern "C" void kernel_launch(void* const* d_in, const int* in_sizes, int n_in,
                              void* d_out, int out_size, void* d_ws, size_t ws_size,
                              hipStream_t stream) {
  (void)in_sizes; (void)n_in; (void)out_size; (void)ws_size;
  const int* tp    = (const int*)d_in[0];
  const int* adj   = (const int*)d_in[1];
  const float* emb = (const float*)d_in[2];
  const int* rows = adj;
  const int* cols = adj + NE;

  char* ws = (char*)d_ws;
  size_t o = 0;
  auto alloc = [&](size_t bytes) -> char* {
    char* p = ws + o;
    o = (o + bytes + 255) & ~(size_t)255;
    return p;
  };
  // zero-initialized region (single memset)
  int* deg       = (int*)alloc(NODE * 4);
  double* Fsum   = (double*)alloc(128 * 8);
  double* Hsum   = (double*)alloc(128 * 8);
  double* S12    = (double*)alloc(2 * 8);
  float* lsum    = (float*)alloc(NROWS * 4);
  size_t zero_bytes = o;
  // rest
  float* G       = (float*)alloc(128 * 128 * 4);
  float* Gpart   = (float*)alloc((size_t)NSBLK * 16384 * 4);
  float* sqn     = (float*)alloc(NODE * 4);
  float* tsqn    = (float*)alloc((size_t)NODE_P * 4);
  float* coefA   = (float*)alloc(NROWS * 4);
  float* coefG   = (float*)alloc(NROWS * 4);
  float* corr    = (float*)alloc(NROWS * 4);
  int* padcol    = (int*)alloc((size_t)NODE * DCAP * 4);
  unsigned short* featb = (unsigned short*)alloc((size_t)NODE_P * HID * 2);
  unsigned short* embb  = (unsigned short*)alloc((size_t)NODE * HID * 2);

  hipMemsetAsync(d_ws, 0, zero_bytes, stream);
  k_prep<<<3750 + (NE + 255) / 256, 256, 0, stream>>>(emb, embb, rows, cols, deg, padcol);
  k_aggregate<<<NODE_P / 4, 256, 0, stream>>>(embb, deg, padcol, featb, sqn, tsqn);
  k_nodestats<<<NSBLK, 256, 0, stream>>>(featb, sqn, Gpart, Fsum, Hsum, S12);
  k_greduce<<<64, 256, 0, stream>>>(Gpart, G);
  k_pairstats<<<NB / 16, 1024, 0, stream>>>(tp, featb, sqn, G, Fsum, Hsum, S12, coefA, coefG, corr);
  k_fused<<<NCHUNK * 32, 256, 0, stream>>>(tp, featb, tsqn, coefA, coefG, lsum);
  k_final<<<1, 1024, 0, stream>>>(lsum, corr, (float*)d_out);
}